// Round 4
// baseline (630.289 us; speedup 1.0000x reference)
//
#include <hip/hip_runtime.h>
#include <hip/hip_fp8.h>
#include <cfloat>

// Problem constants: x (16,2048,256) fp32 -> N=32768 rows; weight (4096,256) fp32.
constexpr int E  = 256;    // quantizing_dim
constexpr int Qn = 4096;   // num_quantizing
constexpr float WSCALE = 4096.0f;   // 2^12 exact

// Hybrid precision GEMM:
//   main:        xh(f16) . wh_s(f16)            K=256, f16 MFMA
//   corrections: [xh8 | xl*2^12] . [wl_ss | wh8] K=512, MX-fp8 MFMA (2x rate)
// acc ends at 2^24*dot; ranking key = fmaf(acc, -2^-23, w2) = w2 - 2*dot.

typedef _Float16 half8  __attribute__((ext_vector_type(8)));
typedef _Float16 half4v __attribute__((ext_vector_type(4)));
typedef float    f32x16 __attribute__((ext_vector_type(16)));
typedef int      int4v  __attribute__((ext_vector_type(4)));
typedef int      int8v  __attribute__((ext_vector_type(8)));

#define GAS __attribute__((address_space(1)))
#define LAS __attribute__((address_space(3)))

static __device__ inline unsigned int to_fp8(float f) {
    __hip_fp8_e4m3 t(f);                 // OCP e4m3fn, RNE+sat
    return (unsigned int)t.__x;
}

// ---------------------------------------------------------------------------
// Fused prep: one 64-lane wave per row (x and w).
// Emits: sumsq, f16 operands (A16/B16, 256 halves/row), fp8 operands
// (A8/B8, 512 bytes/row: two 256-byte segments).
// ---------------------------------------------------------------------------
__global__ __launch_bounds__(256) void prep_kernel(
    const float* __restrict__ x, const float* __restrict__ w,
    _Float16* __restrict__ A16, _Float16* __restrict__ B16,
    unsigned char* __restrict__ A8, unsigned char* __restrict__ B8,
    float* __restrict__ x2, float* __restrict__ w2, int nxblocks)
{
    int blk  = blockIdx.x;
    int sub  = threadIdx.x >> 6;
    int lane = threadIdx.x & 63;
    bool isX = blk < nxblocks;
    int row  = (isX ? blk : blk - nxblocks) * 4 + sub;

    const float* src = isX ? x : w;
    float4 v = *(const float4*)(src + (size_t)row * E + lane * 4);

    float s = v.x * v.x + v.y * v.y + v.z * v.z + v.w * v.w;   // UNSCALED sumsq
    #pragma unroll
    for (int off = 32; off; off >>= 1) s += __shfl_xor(s, off);
    if (lane == 0) (isX ? x2 : w2)[row] = s;

    float sc = isX ? 1.0f : WSCALE;                            // exact pow2
    float4 vs = { v.x * sc, v.y * sc, v.z * sc, v.w * sc };
    half4v h = { (_Float16)vs.x, (_Float16)vs.y, (_Float16)vs.z, (_Float16)vs.w };
    float4 rl = { (vs.x - (float)h.x) * WSCALE, (vs.y - (float)h.y) * WSCALE,
                  (vs.z - (float)h.z) * WSCALE, (vs.w - (float)h.w) * WSCALE };

    // f16 operand
    _Float16* dst16 = (isX ? A16 : B16) + (size_t)row * 256;
    *(half4v*)(dst16 + lane * 4) = h;

    // fp8 operands
    unsigned int pk_main = to_fp8(vs.x) | (to_fp8(vs.y) << 8) |
                           (to_fp8(vs.z) << 16) | (to_fp8(vs.w) << 24);   // xh8 / wh8
    unsigned int pk_res  = to_fp8(rl.x) | (to_fp8(rl.y) << 8) |
                           (to_fp8(rl.z) << 16) | (to_fp8(rl.w) << 24);   // xl*2^12 / wl_ss
    unsigned char* dst8 = (isX ? A8 : B8) + (size_t)row * 512;
    if (isX) {
        *(unsigned int*)(dst8 +       lane * 4) = pk_main;  // seg0: xh8   (pairs wl_ss)
        *(unsigned int*)(dst8 + 256 + lane * 4) = pk_res;   // seg1: xl_s8 (pairs wh8)
    } else {
        *(unsigned int*)(dst8 +       lane * 4) = pk_res;   // seg0: wl_ss
        *(unsigned int*)(dst8 + 256 + lane * 4) = pk_main;  // seg1: wh8
    }
}

// ---------------------------------------------------------------------------
// Main MFMA kernel: block = 128 x-rows x 128 codewords, grid (N/128, Qn/128).
// ---------------------------------------------------------------------------
__device__ inline void merge_top2(float& B1, int& I1, float& B2, int& I2,
                                  float c1, int j1, float c2, int j2) {
    if (c1 < B1 || (c1 == B1 && j1 < I1)) {
        if (B1 < c2 || (B1 == c2 && I1 < j2)) { B2 = B1; I2 = I1; }
        else                                  { B2 = c2; I2 = j2; }
        B1 = c1; I1 = j1;
    } else {
        if (c1 < B2 || (c1 == B2 && j1 < I2)) { B2 = c1; I2 = j1; }
    }
}

union SmemU {
    struct { _Float16 W[128 * 64]; _Float16 X[128 * 64]; } st;  // 32 KB staging
    float4 mergeS[128 * 4];                                      // 8 KB (post-loop)
};

__global__ __launch_bounds__(256, 4) void vq_mfma_kernel(
    const _Float16* __restrict__ A16,      // (N, 256)  xh
    const _Float16* __restrict__ B16,      // (Qn, 256) wh_s
    const unsigned char* __restrict__ A8,  // (N, 512)  [xh8 | xl_s8]
    const unsigned char* __restrict__ B8,  // (Qn, 512) [wl_ss | wh8]
    const float* __restrict__ w2,
    float4* __restrict__ top2)             // (N, Qn/128) {b1,i1,b2,i2}
{
    __shared__ SmemU sm;
    __shared__ float w2s[128];

    const int tid  = threadIdx.x;
    const int w    = tid >> 6;
    const int lane = tid & 63;
    const int l31  = lane & 31;
    const int lh   = lane >> 5;          // k-half select
    const int rb   = blockIdx.x;         // row band (128 x-rows)
    const int cg   = blockIdx.y;         // col group (128 codewords)

    if (tid < 128) w2s[tid] = w2[cg * 128 + tid];

    const int wr = (w & 1) * 64;         // wave's x-row quadrant base
    const int wc = (w >> 1) * 64;        // wave's codeword quadrant base

    f32x16 acc[2][2];
    #pragma unroll
    for (int f = 0; f < 2; ++f)
        #pragma unroll
        for (int g = 0; g < 2; ++g)
            #pragma unroll
            for (int r = 0; r < 16; ++r) acc[f][g][r] = 0.0f;

    const _Float16* Ab16 = A16 + (size_t)rb * 128 * 256;
    const _Float16* Bb16 = B16 + (size_t)cg * 128 * 256;
    const unsigned char* Ab8 = A8 + (size_t)rb * 128 * 512;
    const unsigned char* Bb8 = B8 + (size_t)cg * 128 * 512;

    const int srow = lane >> 3;   // staging: row-in-8 group
    const int schk = lane & 7;    // staging: dest 16B chunk

    // ---------------- Phase 1: f16 main term, K=256 (4 kt of K=64) ----------
    for (int kt = 0; kt < 4; ++kt) {
        __syncthreads();
        #pragma unroll
        for (int inst = 0; inst < 4; ++inst) {
            int drow = w * 32 + inst * 8 + srow;          // 0..127
            int gchk = schk ^ (drow & 7);                 // source chunk swizzle
            const _Float16* gW = Bb16 + (size_t)drow * 256 + kt * 64 + gchk * 8;
            const _Float16* gX = Ab16 + (size_t)drow * 256 + kt * 64 + gchk * 8;
            __builtin_amdgcn_global_load_lds((const GAS void*)gW,
                (LAS void*)(sm.st.W + w * 2048 + inst * 512), 16, 0, 0);
            __builtin_amdgcn_global_load_lds((const GAS void*)gX,
                (LAS void*)(sm.st.X + w * 2048 + inst * 512), 16, 0, 0);
        }
        __syncthreads();

        #pragma unroll
        for (int s = 0; s < 4; ++s) {
            const int kc = 2 * s + lh;
            half8 wf[2], xf[2];
            #pragma unroll
            for (int f = 0; f < 2; ++f) {
                int fr = wc + 32 * f + l31;
                wf[f] = *(const half8*)(sm.st.W + fr * 64 + ((kc ^ (fr & 7)) << 3));
                int xr = wr + 32 * f + l31;
                xf[f] = *(const half8*)(sm.st.X + xr * 64 + ((kc ^ (xr & 7)) << 3));
            }
            #pragma unroll
            for (int f = 0; f < 2; ++f)
                #pragma unroll
                for (int g = 0; g < 2; ++g)
                    acc[f][g] = __builtin_amdgcn_mfma_f32_32x32x16_f16(
                        wf[f], xf[g], acc[f][g], 0, 0, 0);
        }
    }

    // rescale: acc (dot*2^12) -> dot*2^24, so fp8 MFMAs accumulate on top
    #pragma unroll
    for (int f = 0; f < 2; ++f)
        #pragma unroll
        for (int g = 0; g < 2; ++g)
            acc[f][g] *= WSCALE;

    // ------------- Phase 2: fp8 corrections, K=512 (4 kt of K=128) ----------
    const char* ldsW8 = (const char*)sm.st.W;
    const char* ldsX8 = (const char*)sm.st.X;
    for (int kt = 0; kt < 4; ++kt) {
        __syncthreads();
        #pragma unroll
        for (int inst = 0; inst < 4; ++inst) {
            int drow = w * 32 + inst * 8 + srow;
            int gchk = schk ^ (drow & 7);
            const unsigned char* gW = Bb8 + (size_t)drow * 512 + kt * 128 + gchk * 16;
            const unsigned char* gX = Ab8 + (size_t)drow * 512 + kt * 128 + gchk * 16;
            __builtin_amdgcn_global_load_lds((const GAS void*)gW,
                (LAS void*)(sm.st.W + w * 2048 + inst * 512), 16, 0, 0);
            __builtin_amdgcn_global_load_lds((const GAS void*)gX,
                (LAS void*)(sm.st.X + w * 2048 + inst * 512), 16, 0, 0);
        }
        __syncthreads();

        #pragma unroll
        for (int ks = 0; ks < 2; ++ks) {           // two K=64 steps per kt
            const int c0 = 4 * ks + 2 * lh;        // lane's first 16B chunk
            int8v xf8[2];
            #pragma unroll
            for (int g = 0; g < 2; ++g) {
                int xr = wr + 32 * g + l31;
                const char* px = ldsX8 + xr * 128;
                int4v lo = *(const int4v*)(px + (( c0      ^ (xr & 7)) << 4));
                int4v hi = *(const int4v*)(px + (((c0 + 1) ^ (xr & 7)) << 4));
                #pragma unroll
                for (int t = 0; t < 4; ++t) { xf8[g][t] = lo[t]; xf8[g][4 + t] = hi[t]; }
            }
            #pragma unroll
            for (int f = 0; f < 2; ++f) {
                int fr = wc + 32 * f + l31;
                const char* pw = ldsW8 + fr * 128;
                int4v lo = *(const int4v*)(pw + (( c0      ^ (fr & 7)) << 4));
                int4v hi = *(const int4v*)(pw + (((c0 + 1) ^ (fr & 7)) << 4));
                int8v wf8;
                #pragma unroll
                for (int t = 0; t < 4; ++t) { wf8[t] = lo[t]; wf8[4 + t] = hi[t]; }
                #pragma unroll
                for (int g = 0; g < 2; ++g)
                    acc[f][g] = __builtin_amdgcn_mfma_scale_f32_32x32x64_f8f6f4(
                        wf8, xf8[g], acc[f][g],
                        0, 0,                      // cbsz=fp8(A), blgp=fp8(B)
                        0, 0x7F7F7F7F,             // scale A = 1.0 (e8m0 127)
                        0, 0x7F7F7F7F);            // scale B = 1.0
            }
        }
    }

    // ---- epilogue: key = w2 - 2*dot = fmaf(acc, -2^-23, w2); top-2 ----
    constexpr float KNEG = -2.0f / (4096.0f * 4096.0f * 4096.0f) * 2048.0f; // -2^-23
    float b1[2], b2[2]; int i1[2], i2[2];
    #pragma unroll
    for (int g = 0; g < 2; ++g) { b1[g] = FLT_MAX; b2[g] = FLT_MAX; i1[g] = 0x7FFFFFFF; i2[g] = 0x7FFFFFFF; }

    #pragma unroll
    for (int f = 0; f < 2; ++f)
        #pragma unroll
        for (int r = 0; r < 16; ++r) {
            int m  = (r & 3) + 8 * (r >> 2) + 4 * lh;     // C-row mapping (32x32)
            int ql = wc + 32 * f + m;
            float w2c = w2s[ql];
            int  qg = cg * 128 + ql;
            #pragma unroll
            for (int g = 0; g < 2; ++g) {
                float sd = fmaf(acc[f][g][r], KNEG, w2c);
                if (sd < b1[g]) { b2[g] = b1[g]; i2[g] = i1[g]; b1[g] = sd; i1[g] = qg; }
                else if (sd < b2[g]) { b2[g] = sd; i2[g] = qg; }
            }
        }

    __syncthreads();   // staging reads done -> overlay mergeS

    #pragma unroll
    for (int g = 0; g < 2; ++g) {
        int rrow = wr + 32 * g + l31;
        sm.mergeS[rrow * 4 + ((w >> 1) * 2 + lh)] =
            make_float4(b1[g], __int_as_float(i1[g]), b2[g], __int_as_float(i2[g]));
    }
    __syncthreads();

    if (tid < 128) {
        float4 a0 = sm.mergeS[tid * 4 + 0];
        float B1 = a0.x; int I1 = __float_as_int(a0.y);
        float B2 = a0.z; int I2 = __float_as_int(a0.w);
        #pragma unroll
        for (int sl = 1; sl < 4; ++sl) {
            float4 a = sm.mergeS[tid * 4 + sl];
            merge_top2(B1, I1, B2, I2, a.x, __float_as_int(a.y), a.z, __float_as_int(a.w));
        }
        top2[(size_t)(rb * 128 + tid) * (Qn / 128) + cg] =
            make_float4(B1, __int_as_float(I1), B2, __int_as_float(I2));
    }
}

// ---------------------------------------------------------------------------
// Finalize: merge 32 col-group top-2s, exact fp32 rescore of the survivors
// (reference formula + first-index tie-break), write outputs. Unchanged from
// the round-2/3 validated version.
// ---------------------------------------------------------------------------
__global__ __launch_bounds__(256) void finalize_kernel(
    const float4* __restrict__ top2, const float* __restrict__ x,
    const float* __restrict__ w, const float* __restrict__ x2,
    const float* __restrict__ w2, float* __restrict__ qdata,
    float* __restrict__ qidx)
{
    int row  = blockIdx.x * 4 + (threadIdx.x >> 6);
    int lane = threadIdx.x & 63;

    float4 rec = top2[(size_t)row * (Qn / 128) + (lane >> 1)];
    float b0; int i0;
    if (lane & 1) { b0 = rec.z; i0 = __float_as_int(rec.w); }
    else          { b0 = rec.x; i0 = __float_as_int(rec.y); }

    float b = b0; int i = i0;
    #pragma unroll
    for (int off = 32; off; off >>= 1) {
        float ob = __shfl_xor(b, off); int oi = __shfl_xor(i, off);
        if (ob < b || (ob == b && oi < i)) { b = ob; i = oi; }
    }
    const int I1 = i;

    b = (i0 == I1) ? FLT_MAX : b0; i = (i0 == I1) ? 0x7FFFFFFF : i0;
    #pragma unroll
    for (int off = 32; off; off >>= 1) {
        float ob = __shfl_xor(b, off); int oi = __shfl_xor(i, off);
        if (ob < b || (ob == b && oi < i)) { b = ob; i = oi; }
    }
    const int I2 = i;

    float4 xv  = *(const float4*)(x + (size_t)row * E + lane * 4);
    float4 w1v = *(const float4*)(w + (size_t)I1 * E + lane * 4);
    float4 w2v = *(const float4*)(w + (size_t)I2 * E + lane * 4);
    float d1 = xv.x * w1v.x + xv.y * w1v.y + xv.z * w1v.z + xv.w * w1v.w;
    float d2 = xv.x * w2v.x + xv.y * w2v.y + xv.z * w2v.z + xv.w * w2v.w;
    #pragma unroll
    for (int off = 32; off; off >>= 1) { d1 += __shfl_xor(d1, off); d2 += __shfl_xor(d2, off); }

    float X2 = x2[row];
    float s1 = (X2 - 2.0f * d1) + w2[I1];
    float s2 = (X2 - 2.0f * d2) + w2[I2];
    int win = (s2 < s1) ? I2 : ((s1 < s2) ? I1 : (I1 < I2 ? I1 : I2));

    if (lane == 0) qidx[row] = (float)win;
    *(float4*)(qdata + (size_t)row * E + lane * 4) =
        *(const float4*)(w + (size_t)win * E + lane * 4);
}

// ---------------------------------------------------------------------------
// Round-1 fp32 fallback (only if ws_size too small). Passed absmax 0.
// ---------------------------------------------------------------------------
constexpr int FBM = 64, FBN = 128, FBK = 64, FPAD = 4, FTH = 256;

__global__ __launch_bounds__(64) void row_sumsq_kernel(const float* __restrict__ src,
                                                       float* __restrict__ dst) {
    int row = blockIdx.x, lane = threadIdx.x;
    float4 v = ((const float4*)(src + (size_t)row * E))[lane];
    float s = v.x * v.x + v.y * v.y + v.z * v.z + v.w * v.w;
    #pragma unroll
    for (int off = 32; off > 0; off >>= 1) s += __shfl_down(s, off);
    if (lane == 0) dst[row] = s;
}

__global__ __launch_bounds__(FTH) void vq_fallback_kernel(
    const float* __restrict__ x, const float* __restrict__ w,
    const float* __restrict__ x2, const float* __restrict__ w2,
    float* __restrict__ qdata, float* __restrict__ qidx)
{
    __shared__ float xs[FBM][FBK + FPAD];
    __shared__ float ws[FBN][FBK + FPAD];
    __shared__ float redS[FBM][16];
    __shared__ int   redC[FBM][16];
    __shared__ int   bestC[FBM];

    const int tid = threadIdx.x, tr = tid >> 4, tc = tid & 15;
    const int r0 = blockIdx.x * FBM;
    float best[4]; int bidx[4];
    #pragma unroll
    for (int i = 0; i < 4; ++i) { best[i] = FLT_MAX; bidx[i] = 0x7FFFFFFF; }
    float x2r[4];
    #pragma unroll
    for (int i = 0; i < 4; ++i) x2r[i] = x2[r0 + tr + 16 * i];

    for (int qt = 0; qt < Qn / FBN; ++qt) {
        const int c0 = qt * FBN;
        float acc[4][8];
        #pragma unroll
        for (int i = 0; i < 4; ++i)
            #pragma unroll
            for (int j = 0; j < 8; ++j) acc[i][j] = 0.f;
        for (int kt = 0; kt < E / FBK; ++kt) {
            __syncthreads();
            const int kk = (tid & 15) * 4, rr = tid >> 4;
            #pragma unroll
            for (int m = 0; m < 4; ++m)
                *(float4*)&xs[m * 16 + rr][kk] =
                    *(const float4*)(x + (size_t)(r0 + m * 16 + rr) * E + kt * FBK + kk);
            #pragma unroll
            for (int m = 0; m < 8; ++m)
                *(float4*)&ws[m * 16 + rr][kk] =
                    *(const float4*)(w + (size_t)(c0 + m * 16 + rr) * E + kt * FBK + kk);
            __syncthreads();
            #pragma unroll
            for (int k4 = 0; k4 < FBK / 4; ++k4) {
                float4 a[4], bb[8];
                #pragma unroll
                for (int i = 0; i < 4; ++i) a[i] = *(const float4*)&xs[tr + 16 * i][k4 * 4];
                #pragma unroll
                for (int j = 0; j < 8; ++j) bb[j] = *(const float4*)&ws[tc + 16 * j][k4 * 4];
                #pragma unroll
                for (int i = 0; i < 4; ++i)
                    #pragma unroll
                    for (int j = 0; j < 8; ++j) {
                        acc[i][j] += a[i].x * bb[j].x; acc[i][j] += a[i].y * bb[j].y;
                        acc[i][j] += a[i].z * bb[j].z; acc[i][j] += a[i].w * bb[j].w;
                    }
            }
        }
        #pragma unroll
        for (int i = 0; i < 4; ++i)
            #pragma unroll
            for (int j = 0; j < 8; ++j) {
                int c = c0 + tc + 16 * j;
                float s = (x2r[i] - 2.0f * acc[i][j]) + w2[c];
                if (s < best[i]) { best[i] = s; bidx[i] = c; }
            }
    }
    #pragma unroll
    for (int i = 0; i < 4; ++i) { redS[tr + 16 * i][tc] = best[i]; redC[tr + 16 * i][tc] = bidx[i]; }
    __syncthreads();
    if (tid < FBM) {
        float bs = FLT_MAX; int bc = 0x7FFFFFFF;
        #pragma unroll
        for (int t = 0; t < 16; ++t) {
            float s = redS[tid][t]; int c = redC[tid][t];
            if (s < bs || (s == bs && c < bc)) { bs = s; bc = c; }
        }
        qidx[r0 + tid] = (float)bc; bestC[tid] = bc;
    }
    __syncthreads();
    for (int it = 0; it < FBM / 4; ++it) {
        int row = it * 4 + (tid >> 6), c = bestC[row], kk = (tid & 63) * 4;
        *(float4*)(qdata + (size_t)(r0 + row) * E + kk) = *(const float4*)(w + (size_t)c * E + kk);
    }
}

// ---------------------------------------------------------------------------
extern "C" void kernel_launch(void* const* d_in, const int* in_sizes, int n_in,
                              void* d_out, int out_size, void* d_ws, size_t ws_size,
                              hipStream_t stream) {
    const float* x = (const float*)d_in[0];
    const float* w = (const float*)d_in[1];
    const int N = in_sizes[0] / E;                      // 32768

    float* qdata = (float*)d_out;
    float* qidx  = (float*)d_out + (size_t)N * E;

    size_t off = 0;
    auto carve = [&](size_t bytes) { size_t p = off; off += (bytes + 255) & ~(size_t)255; return p; };
    size_t oA16 = carve((size_t)N  * 256 * sizeof(_Float16));   // 16.8 MB
    size_t oB16 = carve((size_t)Qn * 256 * sizeof(_Float16));   //  2.1 MB
    size_t oA8  = carve((size_t)N  * 512);                      // 16.8 MB
    size_t oB8  = carve((size_t)Qn * 512);                      //  2.1 MB
    size_t ox2  = carve((size_t)N * sizeof(float));
    size_t ow2  = carve((size_t)Qn * sizeof(float));
    size_t oT   = carve((size_t)N * (Qn / 128) * sizeof(float4)); // 16.8 MB

    if (ws_size >= off && (N % 128) == 0) {
        char* ws = (char*)d_ws;
        _Float16* A16 = (_Float16*)(ws + oA16);
        _Float16* B16 = (_Float16*)(ws + oB16);
        unsigned char* A8 = (unsigned char*)(ws + oA8);
        unsigned char* B8 = (unsigned char*)(ws + oB8);
        float* x2    = (float*)(ws + ox2);
        float* w2    = (float*)(ws + ow2);
        float4* top2 = (float4*)(ws + oT);

        prep_kernel<<<N / 4 + Qn / 4, 256, 0, stream>>>(x, w, A16, B16, A8, B8, x2, w2, N / 4);
        vq_mfma_kernel<<<dim3(N / 128, Qn / 128), 256, 0, stream>>>(A16, B16, A8, B8, w2, top2);
        finalize_kernel<<<N / 4, 256, 0, stream>>>(top2, x, w, x2, w2, qdata, qidx);
    } else {
        float* x2 = (float*)d_ws;
        float* w2 = x2 + N;
        row_sumsq_kernel<<<N, 64, 0, stream>>>(x, x2);
        row_sumsq_kernel<<<Qn, 64, 0, stream>>>(w, w2);
        vq_fallback_kernel<<<N / FBM, FTH, 0, stream>>>(x, w, x2, w2, qdata, qidx);
    }
}

// Round 5
// 539.802 us; speedup vs baseline: 1.1676x; 1.1676x over previous
//
#include <hip/hip_runtime.h>
#include <hip/hip_fp8.h>
#include <cfloat>

// Problem constants: x (16,2048,256) fp32 -> N=32768 rows; weight (4096,256) fp32.
constexpr int E  = 256;    // quantizing_dim
constexpr int Qn = 4096;   // num_quantizing
constexpr float WSCALE = 4096.0f;   // 2^12 exact

// Hybrid precision GEMM:
//   main:        xh(f16) . wh_s(f16)            K=256, f16 MFMA
//   corrections: [xh8 | xl*2^12] . [wl_ss | wh8] K=512, MX-fp8 MFMA (2x rate)
// acc ends at 2^24*dot; ranking key = fmaf(acc, -2^-23, w2) = w2 - 2*dot.
// Round-4 lesson: launch_bounds(256,4) capped regs at 128 -> K-loop spilled to
// scratch (WRITE_SIZE 1.25 GB). (256,3) gives 170 regs -> no spill.

typedef _Float16 half8  __attribute__((ext_vector_type(8)));
typedef _Float16 half4v __attribute__((ext_vector_type(4)));
typedef float    f32x16 __attribute__((ext_vector_type(16)));
typedef int      int4v  __attribute__((ext_vector_type(4)));
typedef int      int8v  __attribute__((ext_vector_type(8)));

#define GAS __attribute__((address_space(1)))
#define LAS __attribute__((address_space(3)))

static __device__ inline unsigned int to_fp8(float f) {
    __hip_fp8_e4m3 t(f);                 // OCP e4m3fn, RNE+sat
    return (unsigned int)t.__x;
}

// ---------------------------------------------------------------------------
// Fused prep: one 64-lane wave per row (x and w).
// ---------------------------------------------------------------------------
__global__ __launch_bounds__(256) void prep_kernel(
    const float* __restrict__ x, const float* __restrict__ w,
    _Float16* __restrict__ A16, _Float16* __restrict__ B16,
    unsigned char* __restrict__ A8, unsigned char* __restrict__ B8,
    float* __restrict__ x2, float* __restrict__ w2, int nxblocks)
{
    int blk  = blockIdx.x;
    int sub  = threadIdx.x >> 6;
    int lane = threadIdx.x & 63;
    bool isX = blk < nxblocks;
    int row  = (isX ? blk : blk - nxblocks) * 4 + sub;

    const float* src = isX ? x : w;
    float4 v = *(const float4*)(src + (size_t)row * E + lane * 4);

    float s = v.x * v.x + v.y * v.y + v.z * v.z + v.w * v.w;   // UNSCALED sumsq
    #pragma unroll
    for (int off = 32; off; off >>= 1) s += __shfl_xor(s, off);
    if (lane == 0) (isX ? x2 : w2)[row] = s;

    float sc = isX ? 1.0f : WSCALE;                            // exact pow2
    float4 vs = { v.x * sc, v.y * sc, v.z * sc, v.w * sc };
    half4v h = { (_Float16)vs.x, (_Float16)vs.y, (_Float16)vs.z, (_Float16)vs.w };
    float4 rl = { (vs.x - (float)h.x) * WSCALE, (vs.y - (float)h.y) * WSCALE,
                  (vs.z - (float)h.z) * WSCALE, (vs.w - (float)h.w) * WSCALE };

    _Float16* dst16 = (isX ? A16 : B16) + (size_t)row * 256;
    *(half4v*)(dst16 + lane * 4) = h;

    unsigned int pk_main = to_fp8(vs.x) | (to_fp8(vs.y) << 8) |
                           (to_fp8(vs.z) << 16) | (to_fp8(vs.w) << 24);   // xh8 / wh8
    unsigned int pk_res  = to_fp8(rl.x) | (to_fp8(rl.y) << 8) |
                           (to_fp8(rl.z) << 16) | (to_fp8(rl.w) << 24);   // xl*2^12 / wl_ss
    unsigned char* dst8 = (isX ? A8 : B8) + (size_t)row * 512;
    if (isX) {
        *(unsigned int*)(dst8 +       lane * 4) = pk_main;  // seg0: xh8   (pairs wl_ss)
        *(unsigned int*)(dst8 + 256 + lane * 4) = pk_res;   // seg1: xl_s8 (pairs wh8)
    } else {
        *(unsigned int*)(dst8 +       lane * 4) = pk_res;   // seg0: wl_ss
        *(unsigned int*)(dst8 + 256 + lane * 4) = pk_main;  // seg1: wh8
    }
}

// ---------------------------------------------------------------------------
// Main MFMA kernel: block = 128 x-rows x 128 codewords, grid (N/128, Qn/128).
// ---------------------------------------------------------------------------
__device__ inline void merge_top2(float& B1, int& I1, float& B2, int& I2,
                                  float c1, int j1, float c2, int j2) {
    if (c1 < B1 || (c1 == B1 && j1 < I1)) {
        if (B1 < c2 || (B1 == c2 && I1 < j2)) { B2 = B1; I2 = I1; }
        else                                  { B2 = c2; I2 = j2; }
        B1 = c1; I1 = j1;
    } else {
        if (c1 < B2 || (c1 == B2 && j1 < I2)) { B2 = c1; I2 = j1; }
    }
}

union SmemU {
    struct { _Float16 W[128 * 64]; _Float16 X[128 * 64]; } st;  // 32 KB staging
    float4 mergeS[128 * 4];                                      // 8 KB (post-loop)
};

__global__ __launch_bounds__(256, 3) void vq_mfma_kernel(
    const _Float16* __restrict__ A16,      // (N, 256)  xh
    const _Float16* __restrict__ B16,      // (Qn, 256) wh_s
    const unsigned char* __restrict__ A8,  // (N, 512)  [xh8 | xl_s8]
    const unsigned char* __restrict__ B8,  // (Qn, 512) [wl_ss | wh8]
    const float* __restrict__ w2,
    float4* __restrict__ top2)             // (N, Qn/128) {b1,i1,b2,i2}
{
    __shared__ SmemU sm;
    __shared__ float w2s[128];

    const int tid  = threadIdx.x;
    const int w    = tid >> 6;
    const int lane = tid & 63;
    const int l31  = lane & 31;
    const int lh   = lane >> 5;          // k-half select
    const int rb   = blockIdx.x;         // row band (128 x-rows)
    const int cg   = blockIdx.y;         // col group (128 codewords)

    if (tid < 128) w2s[tid] = w2[cg * 128 + tid];

    const int wr = (w & 1) * 64;         // wave's x-row quadrant base
    const int wc = (w >> 1) * 64;        // wave's codeword quadrant base

    f32x16 acc[2][2];
    #pragma unroll
    for (int f = 0; f < 2; ++f)
        #pragma unroll
        for (int g = 0; g < 2; ++g)
            #pragma unroll
            for (int r = 0; r < 16; ++r) acc[f][g][r] = 0.0f;

    const _Float16* Ab16 = A16 + (size_t)rb * 128 * 256;
    const _Float16* Bb16 = B16 + (size_t)cg * 128 * 256;
    const unsigned char* Ab8 = A8 + (size_t)rb * 128 * 512;
    const unsigned char* Bb8 = B8 + (size_t)cg * 128 * 512;

    const int srow = lane >> 3;   // staging: row-in-8 group
    const int schk = lane & 7;    // staging: dest 16B chunk

    // ---------------- Phase 1: f16 main term, K=256 (4 kt of K=64) ----------
    for (int kt = 0; kt < 4; ++kt) {
        __syncthreads();
        #pragma unroll
        for (int inst = 0; inst < 4; ++inst) {
            int drow = w * 32 + inst * 8 + srow;          // 0..127
            int gchk = schk ^ (drow & 7);                 // source chunk swizzle
            const _Float16* gW = Bb16 + (size_t)drow * 256 + kt * 64 + gchk * 8;
            const _Float16* gX = Ab16 + (size_t)drow * 256 + kt * 64 + gchk * 8;
            __builtin_amdgcn_global_load_lds((const GAS void*)gW,
                (LAS void*)(sm.st.W + w * 2048 + inst * 512), 16, 0, 0);
            __builtin_amdgcn_global_load_lds((const GAS void*)gX,
                (LAS void*)(sm.st.X + w * 2048 + inst * 512), 16, 0, 0);
        }
        __syncthreads();

        #pragma unroll
        for (int s = 0; s < 4; ++s) {
            const int kc = 2 * s + lh;
            half8 wf[2], xf[2];
            #pragma unroll
            for (int f = 0; f < 2; ++f) {
                int fr = wc + 32 * f + l31;
                wf[f] = *(const half8*)(sm.st.W + fr * 64 + ((kc ^ (fr & 7)) << 3));
                int xr = wr + 32 * f + l31;
                xf[f] = *(const half8*)(sm.st.X + xr * 64 + ((kc ^ (xr & 7)) << 3));
            }
            #pragma unroll
            for (int f = 0; f < 2; ++f)
                #pragma unroll
                for (int g = 0; g < 2; ++g)
                    acc[f][g] = __builtin_amdgcn_mfma_f32_32x32x16_f16(
                        wf[f], xf[g], acc[f][g], 0, 0, 0);
        }
    }

    // rescale: acc (dot*2^12) -> dot*2^24, so fp8 MFMAs accumulate on top
    #pragma unroll
    for (int f = 0; f < 2; ++f)
        #pragma unroll
        for (int g = 0; g < 2; ++g)
            acc[f][g] *= WSCALE;

    // ------------- Phase 2: fp8 corrections, K=512 (4 kt of K=128) ----------
    const char* ldsW8 = (const char*)sm.st.W;
    const char* ldsX8 = (const char*)sm.st.X;
    for (int kt = 0; kt < 4; ++kt) {
        __syncthreads();
        #pragma unroll
        for (int inst = 0; inst < 4; ++inst) {
            int drow = w * 32 + inst * 8 + srow;
            int gchk = schk ^ (drow & 7);
            const unsigned char* gW = Bb8 + (size_t)drow * 512 + kt * 128 + gchk * 16;
            const unsigned char* gX = Ab8 + (size_t)drow * 512 + kt * 128 + gchk * 16;
            __builtin_amdgcn_global_load_lds((const GAS void*)gW,
                (LAS void*)(sm.st.W + w * 2048 + inst * 512), 16, 0, 0);
            __builtin_amdgcn_global_load_lds((const GAS void*)gX,
                (LAS void*)(sm.st.X + w * 2048 + inst * 512), 16, 0, 0);
        }
        __syncthreads();

        #pragma unroll
        for (int ks = 0; ks < 2; ++ks) {           // two K=64 steps per kt
            const int c0 = 4 * ks + 2 * lh;        // lane's first 16B chunk
            int8v xf8[2];
            #pragma unroll
            for (int g = 0; g < 2; ++g) {
                int xr = wr + 32 * g + l31;
                const char* px = ldsX8 + xr * 128;
                int4v lo = *(const int4v*)(px + (( c0      ^ (xr & 7)) << 4));
                int4v hi = *(const int4v*)(px + (((c0 + 1) ^ (xr & 7)) << 4));
                #pragma unroll
                for (int t = 0; t < 4; ++t) { xf8[g][t] = lo[t]; xf8[g][4 + t] = hi[t]; }
            }
            #pragma unroll
            for (int f = 0; f < 2; ++f) {
                int fr = wc + 32 * f + l31;
                const char* pw = ldsW8 + fr * 128;
                int4v lo = *(const int4v*)(pw + (( c0      ^ (fr & 7)) << 4));
                int4v hi = *(const int4v*)(pw + (((c0 + 1) ^ (fr & 7)) << 4));
                int8v wf8;
                #pragma unroll
                for (int t = 0; t < 4; ++t) { wf8[t] = lo[t]; wf8[4 + t] = hi[t]; }
                #pragma unroll
                for (int g = 0; g < 2; ++g)
                    acc[f][g] = __builtin_amdgcn_mfma_scale_f32_32x32x64_f8f6f4(
                        wf8, xf8[g], acc[f][g],
                        0, 0,                      // cbsz=fp8(A), blgp=fp8(B)
                        0, 0x7F7F7F7F,             // scale A = 1.0 (e8m0 127)
                        0, 0x7F7F7F7F);            // scale B = 1.0
            }
        }
    }

    // ---- epilogue: key = w2 - 2*dot = fmaf(acc, -2^-23, w2); top-2 ----
    constexpr float KNEG = -2.0f / (4096.0f * 4096.0f * 4096.0f) * 2048.0f; // -2^-23
    float b1[2], b2[2]; int i1[2], i2[2];
    #pragma unroll
    for (int g = 0; g < 2; ++g) { b1[g] = FLT_MAX; b2[g] = FLT_MAX; i1[g] = 0x7FFFFFFF; i2[g] = 0x7FFFFFFF; }

    #pragma unroll
    for (int f = 0; f < 2; ++f)
        #pragma unroll
        for (int r = 0; r < 16; ++r) {
            int m  = (r & 3) + 8 * (r >> 2) + 4 * lh;     // C-row mapping (32x32)
            int ql = wc + 32 * f + m;
            float w2c = w2s[ql];
            int  qg = cg * 128 + ql;
            #pragma unroll
            for (int g = 0; g < 2; ++g) {
                float sd = fmaf(acc[f][g][r], KNEG, w2c);
                if (sd < b1[g]) { b2[g] = b1[g]; i2[g] = i1[g]; b1[g] = sd; i1[g] = qg; }
                else if (sd < b2[g]) { b2[g] = sd; i2[g] = qg; }
            }
        }

    __syncthreads();   // staging reads done -> overlay mergeS

    #pragma unroll
    for (int g = 0; g < 2; ++g) {
        int rrow = wr + 32 * g + l31;
        sm.mergeS[rrow * 4 + ((w >> 1) * 2 + lh)] =
            make_float4(b1[g], __int_as_float(i1[g]), b2[g], __int_as_float(i2[g]));
    }
    __syncthreads();

    if (tid < 128) {
        float4 a0 = sm.mergeS[tid * 4 + 0];
        float B1 = a0.x; int I1 = __float_as_int(a0.y);
        float B2 = a0.z; int I2 = __float_as_int(a0.w);
        #pragma unroll
        for (int sl = 1; sl < 4; ++sl) {
            float4 a = sm.mergeS[tid * 4 + sl];
            merge_top2(B1, I1, B2, I2, a.x, __float_as_int(a.y), a.z, __float_as_int(a.w));
        }
        top2[(size_t)(rb * 128 + tid) * (Qn / 128) + cg] =
            make_float4(B1, __int_as_float(I1), B2, __int_as_float(I2));
    }
}

// ---------------------------------------------------------------------------
// Finalize: merge 32 col-group top-2s, exact fp32 rescore of the survivors
// (reference formula + first-index tie-break), write outputs. Unchanged from
// the round-2/3 validated version.
// ---------------------------------------------------------------------------
__global__ __launch_bounds__(256) void finalize_kernel(
    const float4* __restrict__ top2, const float* __restrict__ x,
    const float* __restrict__ w, const float* __restrict__ x2,
    const float* __restrict__ w2, float* __restrict__ qdata,
    float* __restrict__ qidx)
{
    int row  = blockIdx.x * 4 + (threadIdx.x >> 6);
    int lane = threadIdx.x & 63;

    float4 rec = top2[(size_t)row * (Qn / 128) + (lane >> 1)];
    float b0; int i0;
    if (lane & 1) { b0 = rec.z; i0 = __float_as_int(rec.w); }
    else          { b0 = rec.x; i0 = __float_as_int(rec.y); }

    float b = b0; int i = i0;
    #pragma unroll
    for (int off = 32; off; off >>= 1) {
        float ob = __shfl_xor(b, off); int oi = __shfl_xor(i, off);
        if (ob < b || (ob == b && oi < i)) { b = ob; i = oi; }
    }
    const int I1 = i;

    b = (i0 == I1) ? FLT_MAX : b0; i = (i0 == I1) ? 0x7FFFFFFF : i0;
    #pragma unroll
    for (int off = 32; off; off >>= 1) {
        float ob = __shfl_xor(b, off); int oi = __shfl_xor(i, off);
        if (ob < b || (ob == b && oi < i)) { b = ob; i = oi; }
    }
    const int I2 = i;

    float4 xv  = *(const float4*)(x + (size_t)row * E + lane * 4);
    float4 w1v = *(const float4*)(w + (size_t)I1 * E + lane * 4);
    float4 w2v = *(const float4*)(w + (size_t)I2 * E + lane * 4);
    float d1 = xv.x * w1v.x + xv.y * w1v.y + xv.z * w1v.z + xv.w * w1v.w;
    float d2 = xv.x * w2v.x + xv.y * w2v.y + xv.z * w2v.z + xv.w * w2v.w;
    #pragma unroll
    for (int off = 32; off; off >>= 1) { d1 += __shfl_xor(d1, off); d2 += __shfl_xor(d2, off); }

    float X2 = x2[row];
    float s1 = (X2 - 2.0f * d1) + w2[I1];
    float s2 = (X2 - 2.0f * d2) + w2[I2];
    int win = (s2 < s1) ? I2 : ((s1 < s2) ? I1 : (I1 < I2 ? I1 : I2));

    if (lane == 0) qidx[row] = (float)win;
    *(float4*)(qdata + (size_t)row * E + lane * 4) =
        *(const float4*)(w + (size_t)win * E + lane * 4);
}

// ---------------------------------------------------------------------------
// Round-1 fp32 fallback (only if ws_size too small). Passed absmax 0.
// ---------------------------------------------------------------------------
constexpr int FBM = 64, FBN = 128, FBK = 64, FPAD = 4, FTH = 256;

__global__ __launch_bounds__(64) void row_sumsq_kernel(const float* __restrict__ src,
                                                       float* __restrict__ dst) {
    int row = blockIdx.x, lane = threadIdx.x;
    float4 v = ((const float4*)(src + (size_t)row * E))[lane];
    float s = v.x * v.x + v.y * v.y + v.z * v.z + v.w * v.w;
    #pragma unroll
    for (int off = 32; off > 0; off >>= 1) s += __shfl_down(s, off);
    if (lane == 0) dst[row] = s;
}

__global__ __launch_bounds__(FTH) void vq_fallback_kernel(
    const float* __restrict__ x, const float* __restrict__ w,
    const float* __restrict__ x2, const float* __restrict__ w2,
    float* __restrict__ qdata, float* __restrict__ qidx)
{
    __shared__ float xs[FBM][FBK + FPAD];
    __shared__ float ws[FBN][FBK + FPAD];
    __shared__ float redS[FBM][16];
    __shared__ int   redC[FBM][16];
    __shared__ int   bestC[FBM];

    const int tid = threadIdx.x, tr = tid >> 4, tc = tid & 15;
    const int r0 = blockIdx.x * FBM;
    float best[4]; int bidx[4];
    #pragma unroll
    for (int i = 0; i < 4; ++i) { best[i] = FLT_MAX; bidx[i] = 0x7FFFFFFF; }
    float x2r[4];
    #pragma unroll
    for (int i = 0; i < 4; ++i) x2r[i] = x2[r0 + tr + 16 * i];

    for (int qt = 0; qt < Qn / FBN; ++qt) {
        const int c0 = qt * FBN;
        float acc[4][8];
        #pragma unroll
        for (int i = 0; i < 4; ++i)
            #pragma unroll
            for (int j = 0; j < 8; ++j) acc[i][j] = 0.f;
        for (int kt = 0; kt < E / FBK; ++kt) {
            __syncthreads();
            const int kk = (tid & 15) * 4, rr = tid >> 4;
            #pragma unroll
            for (int m = 0; m < 4; ++m)
                *(float4*)&xs[m * 16 + rr][kk] =
                    *(const float4*)(x + (size_t)(r0 + m * 16 + rr) * E + kt * FBK + kk);
            #pragma unroll
            for (int m = 0; m < 8; ++m)
                *(float4*)&ws[m * 16 + rr][kk] =
                    *(const float4*)(w + (size_t)(c0 + m * 16 + rr) * E + kt * FBK + kk);
            __syncthreads();
            #pragma unroll
            for (int k4 = 0; k4 < FBK / 4; ++k4) {
                float4 a[4], bb[8];
                #pragma unroll
                for (int i = 0; i < 4; ++i) a[i] = *(const float4*)&xs[tr + 16 * i][k4 * 4];
                #pragma unroll
                for (int j = 0; j < 8; ++j) bb[j] = *(const float4*)&ws[tc + 16 * j][k4 * 4];
                #pragma unroll
                for (int i = 0; i < 4; ++i)
                    #pragma unroll
                    for (int j = 0; j < 8; ++j) {
                        acc[i][j] += a[i].x * bb[j].x; acc[i][j] += a[i].y * bb[j].y;
                        acc[i][j] += a[i].z * bb[j].z; acc[i][j] += a[i].w * bb[j].w;
                    }
            }
        }
        #pragma unroll
        for (int i = 0; i < 4; ++i)
            #pragma unroll
            for (int j = 0; j < 8; ++j) {
                int c = c0 + tc + 16 * j;
                float s = (x2r[i] - 2.0f * acc[i][j]) + w2[c];
                if (s < best[i]) { best[i] = s; bidx[i] = c; }
            }
    }
    #pragma unroll
    for (int i = 0; i < 4; ++i) { redS[tr + 16 * i][tc] = best[i]; redC[tr + 16 * i][tc] = bidx[i]; }
    __syncthreads();
    if (tid < FBM) {
        float bs = FLT_MAX; int bc = 0x7FFFFFFF;
        #pragma unroll
        for (int t = 0; t < 16; ++t) {
            float s = redS[tid][t]; int c = redC[tid][t];
            if (s < bs || (s == bs && c < bc)) { bs = s; bc = c; }
        }
        qidx[r0 + tid] = (float)bc; bestC[tid] = bc;
    }
    __syncthreads();
    for (int it = 0; it < FBM / 4; ++it) {
        int row = it * 4 + (tid >> 6), c = bestC[row], kk = (tid & 63) * 4;
        *(float4*)(qdata + (size_t)(r0 + row) * E + kk) = *(const float4*)(w + (size_t)c * E + kk);
    }
}

// ---------------------------------------------------------------------------
extern "C" void kernel_launch(void* const* d_in, const int* in_sizes, int n_in,
                              void* d_out, int out_size, void* d_ws, size_t ws_size,
                              hipStream_t stream) {
    const float* x = (const float*)d_in[0];
    const float* w = (const float*)d_in[1];
    const int N = in_sizes[0] / E;                      // 32768

    float* qdata = (float*)d_out;
    float* qidx  = (float*)d_out + (size_t)N * E;

    size_t off = 0;
    auto carve = [&](size_t bytes) { size_t p = off; off += (bytes + 255) & ~(size_t)255; return p; };
    size_t oA16 = carve((size_t)N  * 256 * sizeof(_Float16));   // 16.8 MB
    size_t oB16 = carve((size_t)Qn * 256 * sizeof(_Float16));   //  2.1 MB
    size_t oA8  = carve((size_t)N  * 512);                      // 16.8 MB
    size_t oB8  = carve((size_t)Qn * 512);                      //  2.1 MB
    size_t ox2  = carve((size_t)N * sizeof(float));
    size_t ow2  = carve((size_t)Qn * sizeof(float));
    size_t oT   = carve((size_t)N * (Qn / 128) * sizeof(float4)); // 16.8 MB

    if (ws_size >= off && (N % 128) == 0) {
        char* ws = (char*)d_ws;
        _Float16* A16 = (_Float16*)(ws + oA16);
        _Float16* B16 = (_Float16*)(ws + oB16);
        unsigned char* A8 = (unsigned char*)(ws + oA8);
        unsigned char* B8 = (unsigned char*)(ws + oB8);
        float* x2    = (float*)(ws + ox2);
        float* w2    = (float*)(ws + ow2);
        float4* top2 = (float4*)(ws + oT);

        prep_kernel<<<N / 4 + Qn / 4, 256, 0, stream>>>(x, w, A16, B16, A8, B8, x2, w2, N / 4);
        vq_mfma_kernel<<<dim3(N / 128, Qn / 128), 256, 0, stream>>>(A16, B16, A8, B8, w2, top2);
        finalize_kernel<<<N / 4, 256, 0, stream>>>(top2, x, w, x2, w2, qdata, qidx);
    } else {
        float* x2 = (float*)d_ws;
        float* w2 = x2 + N;
        row_sumsq_kernel<<<N, 64, 0, stream>>>(x, x2);
        row_sumsq_kernel<<<Qn, 64, 0, stream>>>(w, w2);
        vq_fallback_kernel<<<N / FBM, FTH, 0, stream>>>(x, w, x2, w2, qdata, qidx);
    }
}

// Round 6
// 406.905 us; speedup vs baseline: 1.5490x; 1.3266x over previous
//
#include <hip/hip_runtime.h>
#include <hip/hip_fp8.h>
#include <cfloat>

// Problem constants: x (16,2048,256) fp32 -> N=32768 rows; weight (4096,256) fp32.
constexpr int E  = 256;    // quantizing_dim
constexpr int Qn = 4096;   // num_quantizing
constexpr float WSCALE = 4096.0f;   // 2^12 exact

// Hybrid precision GEMM:
//   main:        xh(f16) . wh_s(f16)            K=256, f16 MFMA
//   corrections: [xh8 | xl*2^12] . [wl_ss | wh8] K=512, MX-fp8 MFMA (2x rate)
// acc ends at 2^24*dot; ranking key = fmaf(acc, -2^-23, w2) = w2 - 2*dot.
// Round-4: (256,4) cap 128 -> massive spill (WRITE 1.25 GB).
// Round-5: (256,3) cap ~170 -> still spilling (WRITE 909 MB; live set ~150+).
// Round-6: (256,2) cap 256 -> spill-free; runtime occupancy follows ACTUAL
// allocation (~150-160 regs -> 3 waves/SIMD), not the bound.

typedef _Float16 half8  __attribute__((ext_vector_type(8)));
typedef _Float16 half4v __attribute__((ext_vector_type(4)));
typedef float    f32x16 __attribute__((ext_vector_type(16)));
typedef int      int4v  __attribute__((ext_vector_type(4)));
typedef int      int8v  __attribute__((ext_vector_type(8)));

#define GAS __attribute__((address_space(1)))
#define LAS __attribute__((address_space(3)))

static __device__ inline unsigned int to_fp8(float f) {
    __hip_fp8_e4m3 t(f);                 // OCP e4m3fn, RNE+sat
    return (unsigned int)t.__x;
}

// ---------------------------------------------------------------------------
// Fused prep: one 64-lane wave per row (x and w).
// ---------------------------------------------------------------------------
__global__ __launch_bounds__(256) void prep_kernel(
    const float* __restrict__ x, const float* __restrict__ w,
    _Float16* __restrict__ A16, _Float16* __restrict__ B16,
    unsigned char* __restrict__ A8, unsigned char* __restrict__ B8,
    float* __restrict__ x2, float* __restrict__ w2, int nxblocks)
{
    int blk  = blockIdx.x;
    int sub  = threadIdx.x >> 6;
    int lane = threadIdx.x & 63;
    bool isX = blk < nxblocks;
    int row  = (isX ? blk : blk - nxblocks) * 4 + sub;

    const float* src = isX ? x : w;
    float4 v = *(const float4*)(src + (size_t)row * E + lane * 4);

    float s = v.x * v.x + v.y * v.y + v.z * v.z + v.w * v.w;   // UNSCALED sumsq
    #pragma unroll
    for (int off = 32; off; off >>= 1) s += __shfl_xor(s, off);
    if (lane == 0) (isX ? x2 : w2)[row] = s;

    float sc = isX ? 1.0f : WSCALE;                            // exact pow2
    float4 vs = { v.x * sc, v.y * sc, v.z * sc, v.w * sc };
    half4v h = { (_Float16)vs.x, (_Float16)vs.y, (_Float16)vs.z, (_Float16)vs.w };
    float4 rl = { (vs.x - (float)h.x) * WSCALE, (vs.y - (float)h.y) * WSCALE,
                  (vs.z - (float)h.z) * WSCALE, (vs.w - (float)h.w) * WSCALE };

    _Float16* dst16 = (isX ? A16 : B16) + (size_t)row * 256;
    *(half4v*)(dst16 + lane * 4) = h;

    unsigned int pk_main = to_fp8(vs.x) | (to_fp8(vs.y) << 8) |
                           (to_fp8(vs.z) << 16) | (to_fp8(vs.w) << 24);   // xh8 / wh8
    unsigned int pk_res  = to_fp8(rl.x) | (to_fp8(rl.y) << 8) |
                           (to_fp8(rl.z) << 16) | (to_fp8(rl.w) << 24);   // xl*2^12 / wl_ss
    unsigned char* dst8 = (isX ? A8 : B8) + (size_t)row * 512;
    if (isX) {
        *(unsigned int*)(dst8 +       lane * 4) = pk_main;  // seg0: xh8   (pairs wl_ss)
        *(unsigned int*)(dst8 + 256 + lane * 4) = pk_res;   // seg1: xl_s8 (pairs wh8)
    } else {
        *(unsigned int*)(dst8 +       lane * 4) = pk_res;   // seg0: wl_ss
        *(unsigned int*)(dst8 + 256 + lane * 4) = pk_main;  // seg1: wh8
    }
}

// ---------------------------------------------------------------------------
// Main MFMA kernel: block = 128 x-rows x 128 codewords, grid (N/128, Qn/128).
// ---------------------------------------------------------------------------
__device__ inline void merge_top2(float& B1, int& I1, float& B2, int& I2,
                                  float c1, int j1, float c2, int j2) {
    if (c1 < B1 || (c1 == B1 && j1 < I1)) {
        if (B1 < c2 || (B1 == c2 && I1 < j2)) { B2 = B1; I2 = I1; }
        else                                  { B2 = c2; I2 = j2; }
        B1 = c1; I1 = j1;
    } else {
        if (c1 < B2 || (c1 == B2 && j1 < I2)) { B2 = c1; I2 = j1; }
    }
}

union SmemU {
    struct { _Float16 W[128 * 64]; _Float16 X[128 * 64]; } st;  // 32 KB staging
    float4 mergeS[128 * 4];                                      // 8 KB (post-loop)
};

__global__ __launch_bounds__(256, 2) void vq_mfma_kernel(
    const _Float16* __restrict__ A16,      // (N, 256)  xh
    const _Float16* __restrict__ B16,      // (Qn, 256) wh_s
    const unsigned char* __restrict__ A8,  // (N, 512)  [xh8 | xl_s8]
    const unsigned char* __restrict__ B8,  // (Qn, 512) [wl_ss | wh8]
    const float* __restrict__ w2,
    float4* __restrict__ top2)             // (N, Qn/128) {b1,i1,b2,i2}
{
    __shared__ SmemU sm;
    __shared__ float w2s[128];

    const int tid  = threadIdx.x;
    const int w    = tid >> 6;
    const int lane = tid & 63;
    const int l31  = lane & 31;
    const int lh   = lane >> 5;          // k-half select
    const int rb   = blockIdx.x;         // row band (128 x-rows)
    const int cg   = blockIdx.y;         // col group (128 codewords)

    if (tid < 128) w2s[tid] = w2[cg * 128 + tid];

    const int wr = (w & 1) * 64;         // wave's x-row quadrant base
    const int wc = (w >> 1) * 64;        // wave's codeword quadrant base

    f32x16 acc[2][2];
    #pragma unroll
    for (int f = 0; f < 2; ++f)
        #pragma unroll
        for (int g = 0; g < 2; ++g)
            #pragma unroll
            for (int r = 0; r < 16; ++r) acc[f][g][r] = 0.0f;

    const _Float16* Ab16 = A16 + (size_t)rb * 128 * 256;
    const _Float16* Bb16 = B16 + (size_t)cg * 128 * 256;
    const unsigned char* Ab8 = A8 + (size_t)rb * 128 * 512;
    const unsigned char* Bb8 = B8 + (size_t)cg * 128 * 512;

    const int srow = lane >> 3;   // staging: row-in-8 group
    const int schk = lane & 7;    // staging: dest 16B chunk

    // ---------------- Phase 1: f16 main term, K=256 (4 kt of K=64) ----------
    for (int kt = 0; kt < 4; ++kt) {
        __syncthreads();
        #pragma unroll
        for (int inst = 0; inst < 4; ++inst) {
            int drow = w * 32 + inst * 8 + srow;          // 0..127
            int gchk = schk ^ (drow & 7);                 // source chunk swizzle
            const _Float16* gW = Bb16 + (size_t)drow * 256 + kt * 64 + gchk * 8;
            const _Float16* gX = Ab16 + (size_t)drow * 256 + kt * 64 + gchk * 8;
            __builtin_amdgcn_global_load_lds((const GAS void*)gW,
                (LAS void*)(sm.st.W + w * 2048 + inst * 512), 16, 0, 0);
            __builtin_amdgcn_global_load_lds((const GAS void*)gX,
                (LAS void*)(sm.st.X + w * 2048 + inst * 512), 16, 0, 0);
        }
        __syncthreads();

        #pragma unroll
        for (int s = 0; s < 4; ++s) {
            const int kc = 2 * s + lh;
            half8 wf[2], xf[2];
            #pragma unroll
            for (int f = 0; f < 2; ++f) {
                int fr = wc + 32 * f + l31;
                wf[f] = *(const half8*)(sm.st.W + fr * 64 + ((kc ^ (fr & 7)) << 3));
                int xr = wr + 32 * f + l31;
                xf[f] = *(const half8*)(sm.st.X + xr * 64 + ((kc ^ (xr & 7)) << 3));
            }
            #pragma unroll
            for (int f = 0; f < 2; ++f)
                #pragma unroll
                for (int g = 0; g < 2; ++g)
                    acc[f][g] = __builtin_amdgcn_mfma_f32_32x32x16_f16(
                        wf[f], xf[g], acc[f][g], 0, 0, 0);
        }
    }

    // rescale: acc (dot*2^12) -> dot*2^24, so fp8 MFMAs accumulate on top
    #pragma unroll
    for (int f = 0; f < 2; ++f)
        #pragma unroll
        for (int g = 0; g < 2; ++g)
            acc[f][g] *= WSCALE;

    // ------------- Phase 2: fp8 corrections, K=512 (4 kt of K=128) ----------
    const char* ldsW8 = (const char*)sm.st.W;
    const char* ldsX8 = (const char*)sm.st.X;
    for (int kt = 0; kt < 4; ++kt) {
        __syncthreads();
        #pragma unroll
        for (int inst = 0; inst < 4; ++inst) {
            int drow = w * 32 + inst * 8 + srow;
            int gchk = schk ^ (drow & 7);
            const unsigned char* gW = Bb8 + (size_t)drow * 512 + kt * 128 + gchk * 16;
            const unsigned char* gX = Ab8 + (size_t)drow * 512 + kt * 128 + gchk * 16;
            __builtin_amdgcn_global_load_lds((const GAS void*)gW,
                (LAS void*)(sm.st.W + w * 2048 + inst * 512), 16, 0, 0);
            __builtin_amdgcn_global_load_lds((const GAS void*)gX,
                (LAS void*)(sm.st.X + w * 2048 + inst * 512), 16, 0, 0);
        }
        __syncthreads();

        #pragma unroll
        for (int ks = 0; ks < 2; ++ks) {           // two K=64 steps per kt
            const int c0 = 4 * ks + 2 * lh;        // lane's first 16B chunk
            int8v xf8[2];
            #pragma unroll
            for (int g = 0; g < 2; ++g) {
                int xr = wr + 32 * g + l31;
                const char* px = ldsX8 + xr * 128;
                int4v lo = *(const int4v*)(px + (( c0      ^ (xr & 7)) << 4));
                int4v hi = *(const int4v*)(px + (((c0 + 1) ^ (xr & 7)) << 4));
                #pragma unroll
                for (int t = 0; t < 4; ++t) { xf8[g][t] = lo[t]; xf8[g][4 + t] = hi[t]; }
            }
            #pragma unroll
            for (int f = 0; f < 2; ++f) {
                int fr = wc + 32 * f + l31;
                const char* pw = ldsW8 + fr * 128;
                int4v lo = *(const int4v*)(pw + (( c0      ^ (fr & 7)) << 4));
                int4v hi = *(const int4v*)(pw + (((c0 + 1) ^ (fr & 7)) << 4));
                int8v wf8;
                #pragma unroll
                for (int t = 0; t < 4; ++t) { wf8[t] = lo[t]; wf8[4 + t] = hi[t]; }
                #pragma unroll
                for (int g = 0; g < 2; ++g)
                    acc[f][g] = __builtin_amdgcn_mfma_scale_f32_32x32x64_f8f6f4(
                        wf8, xf8[g], acc[f][g],
                        0, 0,                      // cbsz=fp8(A), blgp=fp8(B)
                        0, 0x7F7F7F7F,             // scale A = 1.0 (e8m0 127)
                        0, 0x7F7F7F7F);            // scale B = 1.0
            }
        }
    }

    // ---- epilogue: key = w2 - 2*dot = fmaf(acc, -2^-23, w2); top-2 ----
    constexpr float KNEG = -2.0f / (4096.0f * 4096.0f * 4096.0f) * 2048.0f; // -2^-23
    float b1[2], b2[2]; int i1[2], i2[2];
    #pragma unroll
    for (int g = 0; g < 2; ++g) { b1[g] = FLT_MAX; b2[g] = FLT_MAX; i1[g] = 0x7FFFFFFF; i2[g] = 0x7FFFFFFF; }

    #pragma unroll
    for (int f = 0; f < 2; ++f)
        #pragma unroll
        for (int r = 0; r < 16; ++r) {
            int m  = (r & 3) + 8 * (r >> 2) + 4 * lh;     // C-row mapping (32x32)
            int ql = wc + 32 * f + m;
            float w2c = w2s[ql];
            int  qg = cg * 128 + ql;
            #pragma unroll
            for (int g = 0; g < 2; ++g) {
                float sd = fmaf(acc[f][g][r], KNEG, w2c);
                if (sd < b1[g]) { b2[g] = b1[g]; i2[g] = i1[g]; b1[g] = sd; i1[g] = qg; }
                else if (sd < b2[g]) { b2[g] = sd; i2[g] = qg; }
            }
        }

    __syncthreads();   // staging reads done -> overlay mergeS

    #pragma unroll
    for (int g = 0; g < 2; ++g) {
        int rrow = wr + 32 * g + l31;
        sm.mergeS[rrow * 4 + ((w >> 1) * 2 + lh)] =
            make_float4(b1[g], __int_as_float(i1[g]), b2[g], __int_as_float(i2[g]));
    }
    __syncthreads();

    if (tid < 128) {
        float4 a0 = sm.mergeS[tid * 4 + 0];
        float B1 = a0.x; int I1 = __float_as_int(a0.y);
        float B2 = a0.z; int I2 = __float_as_int(a0.w);
        #pragma unroll
        for (int sl = 1; sl < 4; ++sl) {
            float4 a = sm.mergeS[tid * 4 + sl];
            merge_top2(B1, I1, B2, I2, a.x, __float_as_int(a.y), a.z, __float_as_int(a.w));
        }
        top2[(size_t)(rb * 128 + tid) * (Qn / 128) + cg] =
            make_float4(B1, __int_as_float(I1), B2, __int_as_float(I2));
    }
}

// ---------------------------------------------------------------------------
// Finalize: merge 32 col-group top-2s, exact fp32 rescore of the survivors
// (reference formula + first-index tie-break), write outputs. Unchanged from
// the round-2/3 validated version.
// ---------------------------------------------------------------------------
__global__ __launch_bounds__(256) void finalize_kernel(
    const float4* __restrict__ top2, const float* __restrict__ x,
    const float* __restrict__ w, const float* __restrict__ x2,
    const float* __restrict__ w2, float* __restrict__ qdata,
    float* __restrict__ qidx)
{
    int row  = blockIdx.x * 4 + (threadIdx.x >> 6);
    int lane = threadIdx.x & 63;

    float4 rec = top2[(size_t)row * (Qn / 128) + (lane >> 1)];
    float b0; int i0;
    if (lane & 1) { b0 = rec.z; i0 = __float_as_int(rec.w); }
    else          { b0 = rec.x; i0 = __float_as_int(rec.y); }

    float b = b0; int i = i0;
    #pragma unroll
    for (int off = 32; off; off >>= 1) {
        float ob = __shfl_xor(b, off); int oi = __shfl_xor(i, off);
        if (ob < b || (ob == b && oi < i)) { b = ob; i = oi; }
    }
    const int I1 = i;

    b = (i0 == I1) ? FLT_MAX : b0; i = (i0 == I1) ? 0x7FFFFFFF : i0;
    #pragma unroll
    for (int off = 32; off; off >>= 1) {
        float ob = __shfl_xor(b, off); int oi = __shfl_xor(i, off);
        if (ob < b || (ob == b && oi < i)) { b = ob; i = oi; }
    }
    const int I2 = i;

    float4 xv  = *(const float4*)(x + (size_t)row * E + lane * 4);
    float4 w1v = *(const float4*)(w + (size_t)I1 * E + lane * 4);
    float4 w2v = *(const float4*)(w + (size_t)I2 * E + lane * 4);
    float d1 = xv.x * w1v.x + xv.y * w1v.y + xv.z * w1v.z + xv.w * w1v.w;
    float d2 = xv.x * w2v.x + xv.y * w2v.y + xv.z * w2v.z + xv.w * w2v.w;
    #pragma unroll
    for (int off = 32; off; off >>= 1) { d1 += __shfl_xor(d1, off); d2 += __shfl_xor(d2, off); }

    float X2 = x2[row];
    float s1 = (X2 - 2.0f * d1) + w2[I1];
    float s2 = (X2 - 2.0f * d2) + w2[I2];
    int win = (s2 < s1) ? I2 : ((s1 < s2) ? I1 : (I1 < I2 ? I1 : I2));

    if (lane == 0) qidx[row] = (float)win;
    *(float4*)(qdata + (size_t)row * E + lane * 4) =
        *(const float4*)(w + (size_t)win * E + lane * 4);
}

// ---------------------------------------------------------------------------
// Round-1 fp32 fallback (only if ws_size too small). Passed absmax 0.
// ---------------------------------------------------------------------------
constexpr int FBM = 64, FBN = 128, FBK = 64, FPAD = 4, FTH = 256;

__global__ __launch_bounds__(64) void row_sumsq_kernel(const float* __restrict__ src,
                                                       float* __restrict__ dst) {
    int row = blockIdx.x, lane = threadIdx.x;
    float4 v = ((const float4*)(src + (size_t)row * E))[lane];
    float s = v.x * v.x + v.y * v.y + v.z * v.z + v.w * v.w;
    #pragma unroll
    for (int off = 32; off > 0; off >>= 1) s += __shfl_down(s, off);
    if (lane == 0) dst[row] = s;
}

__global__ __launch_bounds__(FTH) void vq_fallback_kernel(
    const float* __restrict__ x, const float* __restrict__ w,
    const float* __restrict__ x2, const float* __restrict__ w2,
    float* __restrict__ qdata, float* __restrict__ qidx)
{
    __shared__ float xs[FBM][FBK + FPAD];
    __shared__ float ws[FBN][FBK + FPAD];
    __shared__ float redS[FBM][16];
    __shared__ int   redC[FBM][16];
    __shared__ int   bestC[FBM];

    const int tid = threadIdx.x, tr = tid >> 4, tc = tid & 15;
    const int r0 = blockIdx.x * FBM;
    float best[4]; int bidx[4];
    #pragma unroll
    for (int i = 0; i < 4; ++i) { best[i] = FLT_MAX; bidx[i] = 0x7FFFFFFF; }
    float x2r[4];
    #pragma unroll
    for (int i = 0; i < 4; ++i) x2r[i] = x2[r0 + tr + 16 * i];

    for (int qt = 0; qt < Qn / FBN; ++qt) {
        const int c0 = qt * FBN;
        float acc[4][8];
        #pragma unroll
        for (int i = 0; i < 4; ++i)
            #pragma unroll
            for (int j = 0; j < 8; ++j) acc[i][j] = 0.f;
        for (int kt = 0; kt < E / FBK; ++kt) {
            __syncthreads();
            const int kk = (tid & 15) * 4, rr = tid >> 4;
            #pragma unroll
            for (int m = 0; m < 4; ++m)
                *(float4*)&xs[m * 16 + rr][kk] =
                    *(const float4*)(x + (size_t)(r0 + m * 16 + rr) * E + kt * FBK + kk);
            #pragma unroll
            for (int m = 0; m < 8; ++m)
                *(float4*)&ws[m * 16 + rr][kk] =
                    *(const float4*)(w + (size_t)(c0 + m * 16 + rr) * E + kt * FBK + kk);
            __syncthreads();
            #pragma unroll
            for (int k4 = 0; k4 < FBK / 4; ++k4) {
                float4 a[4], bb[8];
                #pragma unroll
                for (int i = 0; i < 4; ++i) a[i] = *(const float4*)&xs[tr + 16 * i][k4 * 4];
                #pragma unroll
                for (int j = 0; j < 8; ++j) bb[j] = *(const float4*)&ws[tc + 16 * j][k4 * 4];
                #pragma unroll
                for (int i = 0; i < 4; ++i)
                    #pragma unroll
                    for (int j = 0; j < 8; ++j) {
                        acc[i][j] += a[i].x * bb[j].x; acc[i][j] += a[i].y * bb[j].y;
                        acc[i][j] += a[i].z * bb[j].z; acc[i][j] += a[i].w * bb[j].w;
                    }
            }
        }
        #pragma unroll
        for (int i = 0; i < 4; ++i)
            #pragma unroll
            for (int j = 0; j < 8; ++j) {
                int c = c0 + tc + 16 * j;
                float s = (x2r[i] - 2.0f * acc[i][j]) + w2[c];
                if (s < best[i]) { best[i] = s; bidx[i] = c; }
            }
    }
    #pragma unroll
    for (int i = 0; i < 4; ++i) { redS[tr + 16 * i][tc] = best[i]; redC[tr + 16 * i][tc] = bidx[i]; }
    __syncthreads();
    if (tid < FBM) {
        float bs = FLT_MAX; int bc = 0x7FFFFFFF;
        #pragma unroll
        for (int t = 0; t < 16; ++t) {
            float s = redS[tid][t]; int c = redC[tid][t];
            if (s < bs || (s == bs && c < bc)) { bs = s; bc = c; }
        }
        qidx[r0 + tid] = (float)bc; bestC[tid] = bc;
    }
    __syncthreads();
    for (int it = 0; it < FBM / 4; ++it) {
        int row = it * 4 + (tid >> 6), c = bestC[row], kk = (tid & 63) * 4;
        *(float4*)(qdata + (size_t)(r0 + row) * E + kk) = *(const float4*)(w + (size_t)c * E + kk);
    }
}

// ---------------------------------------------------------------------------
extern "C" void kernel_launch(void* const* d_in, const int* in_sizes, int n_in,
                              void* d_out, int out_size, void* d_ws, size_t ws_size,
                              hipStream_t stream) {
    const float* x = (const float*)d_in[0];
    const float* w = (const float*)d_in[1];
    const int N = in_sizes[0] / E;                      // 32768

    float* qdata = (float*)d_out;
    float* qidx  = (float*)d_out + (size_t)N * E;

    size_t off = 0;
    auto carve = [&](size_t bytes) { size_t p = off; off += (bytes + 255) & ~(size_t)255; return p; };
    size_t oA16 = carve((size_t)N  * 256 * sizeof(_Float16));   // 16.8 MB
    size_t oB16 = carve((size_t)Qn * 256 * sizeof(_Float16));   //  2.1 MB
    size_t oA8  = carve((size_t)N  * 512);                      // 16.8 MB
    size_t oB8  = carve((size_t)Qn * 512);                      //  2.1 MB
    size_t ox2  = carve((size_t)N * sizeof(float));
    size_t ow2  = carve((size_t)Qn * sizeof(float));
    size_t oT   = carve((size_t)N * (Qn / 128) * sizeof(float4)); // 16.8 MB

    if (ws_size >= off && (N % 128) == 0) {
        char* ws = (char*)d_ws;
        _Float16* A16 = (_Float16*)(ws + oA16);
        _Float16* B16 = (_Float16*)(ws + oB16);
        unsigned char* A8 = (unsigned char*)(ws + oA8);
        unsigned char* B8 = (unsigned char*)(ws + oB8);
        float* x2    = (float*)(ws + ox2);
        float* w2    = (float*)(ws + ow2);
        float4* top2 = (float4*)(ws + oT);

        prep_kernel<<<N / 4 + Qn / 4, 256, 0, stream>>>(x, w, A16, B16, A8, B8, x2, w2, N / 4);
        vq_mfma_kernel<<<dim3(N / 128, Qn / 128), 256, 0, stream>>>(A16, B16, A8, B8, w2, top2);
        finalize_kernel<<<N / 4, 256, 0, stream>>>(top2, x, w, x2, w2, qdata, qidx);
    } else {
        float* x2 = (float*)d_ws;
        float* w2 = x2 + N;
        row_sumsq_kernel<<<N, 64, 0, stream>>>(x, x2);
        row_sumsq_kernel<<<Qn, 64, 0, stream>>>(w, w2);
        vq_fallback_kernel<<<N / FBM, FTH, 0, stream>>>(x, w, x2, w2, qdata, qidx);
    }
}

// Round 7
// 222.462 us; speedup vs baseline: 2.8332x; 1.8291x over previous
//
#include <hip/hip_runtime.h>
#include <cfloat>
#include <climits>

// Problem constants: x (16,2048,256) fp32 -> N=32768 rows; weight (4096,256) fp32.
constexpr int E  = 256;    // quantizing_dim
constexpr int Qn = 4096;   // num_quantizing
constexpr float WSCALE = 4096.0f;   // 2^12 exact pow2 (keeps f16 products well-scaled)

// Strategy (round 7): single f16 GEMM (K=256) for the approx ranking key
//   key = w2 - 2*dot_f16   (acc = 4096*dot; key = fmaf(acc, -2^-11, w2))
// Key noise ~1.5e-5 max; rescue via per-lane top-2 -> per-colgroup top-4 ->
// global top-4 exact fp32 rescore (reference formula + lex tie-break).
// P(reference argmin outside top-4) ~ 1e-11/row. No fp8 phase -> no spill
// (rounds 4-6: scaled-MFMA hybrid spilled 0.24-1.25 GB scratch at any cap).

typedef _Float16 half8  __attribute__((ext_vector_type(8)));
typedef _Float16 half4v __attribute__((ext_vector_type(4)));
typedef float    f32x16 __attribute__((ext_vector_type(16)));

#define GAS __attribute__((address_space(1)))
#define LAS __attribute__((address_space(3)))

__device__ inline bool lexlt(float a, int ai, float b, int bi) {
    return a < b || (a == b && ai < bi);
}

// ---------------------------------------------------------------------------
// Prep: one 64-lane wave per row (x and w). Emits f16 operand + sumsq.
// ---------------------------------------------------------------------------
__global__ __launch_bounds__(256) void prep_kernel(
    const float* __restrict__ x, const float* __restrict__ w,
    _Float16* __restrict__ A16, _Float16* __restrict__ B16,
    float* __restrict__ x2, float* __restrict__ w2, int nxblocks)
{
    int blk  = blockIdx.x;
    int sub  = threadIdx.x >> 6;
    int lane = threadIdx.x & 63;
    bool isX = blk < nxblocks;
    int row  = (isX ? blk : blk - nxblocks) * 4 + sub;

    const float* src = isX ? x : w;
    float4 v = *(const float4*)(src + (size_t)row * E + lane * 4);

    float s = v.x * v.x + v.y * v.y + v.z * v.z + v.w * v.w;   // UNSCALED sumsq
    #pragma unroll
    for (int off = 32; off; off >>= 1) s += __shfl_xor(s, off);
    if (lane == 0) (isX ? x2 : w2)[row] = s;

    float sc = isX ? 1.0f : WSCALE;                            // exact pow2
    half4v h = { (_Float16)(v.x * sc), (_Float16)(v.y * sc),
                 (_Float16)(v.z * sc), (_Float16)(v.w * sc) };
    _Float16* dst16 = (isX ? A16 : B16) + (size_t)row * 256;
    *(half4v*)(dst16 + lane * 4) = h;
}

// ---------------------------------------------------------------------------
// Main MFMA kernel: block = 128 x-rows x 128 codewords, grid (N/128, Qn/128).
// Round-3 validated phase-1 structure, K=256 (4 kt). Epilogue: per-lane top-2,
// per-block merge to per-row TOP-4, written to top4 workspace (2 float4/rec).
// ---------------------------------------------------------------------------
__device__ inline void ins4(float K[4], int I[4], float k, int i) {
    #pragma unroll
    for (int t = 0; t < 4; ++t) {
        if (lexlt(k, i, K[t], I[t])) {
            float tk = K[t]; int ti = I[t];
            K[t] = k; I[t] = i; k = tk; i = ti;
        }
    }
}

union SmemU {
    struct { _Float16 W[128 * 64]; _Float16 X[128 * 64]; } st;  // 32 KB staging
    float4 mergeS[128 * 4];                                      // 8 KB (post-loop)
};

__global__ __launch_bounds__(256, 4) void vq_mfma_kernel(
    const _Float16* __restrict__ A16,      // (N, 256)  xh
    const _Float16* __restrict__ B16,      // (Qn, 256) wh_s
    const float* __restrict__ w2,
    float4* __restrict__ top4)             // (N, 32, 2) {k0,i0,k1,i1},{k2,i2,k3,i3}
{
    __shared__ SmemU sm;
    __shared__ float w2s[128];

    const int tid  = threadIdx.x;
    const int w    = tid >> 6;
    const int lane = tid & 63;
    const int l31  = lane & 31;
    const int lh   = lane >> 5;          // k-half select
    const int rb   = blockIdx.x;         // row band (128 x-rows)
    const int cg   = blockIdx.y;         // col group (128 codewords)

    if (tid < 128) w2s[tid] = w2[cg * 128 + tid];

    const int wr = (w & 1) * 64;         // wave's x-row quadrant base
    const int wc = (w >> 1) * 64;        // wave's codeword quadrant base

    f32x16 acc[2][2];
    #pragma unroll
    for (int f = 0; f < 2; ++f)
        #pragma unroll
        for (int g = 0; g < 2; ++g)
            #pragma unroll
            for (int r = 0; r < 16; ++r) acc[f][g][r] = 0.0f;

    const _Float16* Ab16 = A16 + (size_t)rb * 128 * 256;
    const _Float16* Bb16 = B16 + (size_t)cg * 128 * 256;

    const int srow = lane >> 3;   // staging: row-in-8 group
    const int schk = lane & 7;    // staging: dest 16B chunk

    for (int kt = 0; kt < 4; ++kt) {
        __syncthreads();
        #pragma unroll
        for (int inst = 0; inst < 4; ++inst) {
            int drow = w * 32 + inst * 8 + srow;          // 0..127
            int gchk = schk ^ (drow & 7);                 // source chunk swizzle
            const _Float16* gW = Bb16 + (size_t)drow * 256 + kt * 64 + gchk * 8;
            const _Float16* gX = Ab16 + (size_t)drow * 256 + kt * 64 + gchk * 8;
            __builtin_amdgcn_global_load_lds((const GAS void*)gW,
                (LAS void*)(sm.st.W + w * 2048 + inst * 512), 16, 0, 0);
            __builtin_amdgcn_global_load_lds((const GAS void*)gX,
                (LAS void*)(sm.st.X + w * 2048 + inst * 512), 16, 0, 0);
        }
        __syncthreads();

        #pragma unroll
        for (int s = 0; s < 4; ++s) {
            const int kc = 2 * s + lh;
            half8 wf[2], xf[2];
            #pragma unroll
            for (int f = 0; f < 2; ++f) {
                int fr = wc + 32 * f + l31;
                wf[f] = *(const half8*)(sm.st.W + fr * 64 + ((kc ^ (fr & 7)) << 3));
                int xr = wr + 32 * f + l31;
                xf[f] = *(const half8*)(sm.st.X + xr * 64 + ((kc ^ (xr & 7)) << 3));
            }
            #pragma unroll
            for (int f = 0; f < 2; ++f)
                #pragma unroll
                for (int g = 0; g < 2; ++g)
                    acc[f][g] = __builtin_amdgcn_mfma_f32_32x32x16_f16(
                        wf[f], xf[g], acc[f][g], 0, 0, 0);
        }
    }

    // ---- epilogue: key = w2 - 2*dot = fmaf(acc, -2^-11, w2); per-lane top-2 ----
    constexpr float KNEG = -2.0f / WSCALE;   // exact: -2^-11
    float b1[2], b2[2]; int i1[2], i2[2];
    #pragma unroll
    for (int g = 0; g < 2; ++g) { b1[g] = FLT_MAX; b2[g] = FLT_MAX; i1[g] = 0x7FFFFFFF; i2[g] = 0x7FFFFFFF; }

    #pragma unroll
    for (int f = 0; f < 2; ++f)
        #pragma unroll
        for (int r = 0; r < 16; ++r) {
            int m  = (r & 3) + 8 * (r >> 2) + 4 * lh;     // C-row mapping (32x32)
            int ql = wc + 32 * f + m;
            float w2c = w2s[ql];
            int  qg = cg * 128 + ql;
            #pragma unroll
            for (int g = 0; g < 2; ++g) {
                float sd = fmaf(acc[f][g][r], KNEG, w2c);
                if (sd < b1[g]) { b2[g] = b1[g]; i2[g] = i1[g]; b1[g] = sd; i1[g] = qg; }
                else if (sd < b2[g]) { b2[g] = sd; i2[g] = qg; }
            }
        }

    __syncthreads();   // staging reads done -> overlay mergeS

    #pragma unroll
    for (int g = 0; g < 2; ++g) {
        int rrow = wr + 32 * g + l31;
        sm.mergeS[rrow * 4 + ((w >> 1) * 2 + lh)] =
            make_float4(b1[g], __int_as_float(i1[g]), b2[g], __int_as_float(i2[g]));
    }
    __syncthreads();

    if (tid < 128) {
        float K[4] = { FLT_MAX, FLT_MAX, FLT_MAX, FLT_MAX };
        int   I[4] = { INT_MAX, INT_MAX, INT_MAX, INT_MAX };
        #pragma unroll
        for (int sl = 0; sl < 4; ++sl) {
            float4 a = sm.mergeS[tid * 4 + sl];
            ins4(K, I, a.x, __float_as_int(a.y));
            ins4(K, I, a.z, __float_as_int(a.w));
        }
        size_t base = ((size_t)(rb * 128 + tid) * 32 + cg) * 2;
        top4[base + 0] = make_float4(K[0], __int_as_float(I[0]), K[1], __int_as_float(I[1]));
        top4[base + 1] = make_float4(K[2], __int_as_float(I[2]), K[3], __int_as_float(I[3]));
    }
}

// ---------------------------------------------------------------------------
// Finalize: per row merge 32 colgroup top-4s (128 candidates), take global
// top-4 by approx key, exact fp32 rescore (reference formula + first-index
// tie-break), write outputs. One 64-lane wave per row.
// ---------------------------------------------------------------------------
__global__ __launch_bounds__(256) void finalize_kernel(
    const float4* __restrict__ top4, const float* __restrict__ x,
    const float* __restrict__ w, const float* __restrict__ x2,
    const float* __restrict__ w2, float* __restrict__ qdata,
    float* __restrict__ qidx)
{
    int row  = blockIdx.x * 4 + (threadIdx.x >> 6);
    int lane = threadIdx.x & 63;

    // lane -> record (cg = lane>>1, half = lane&1); each record = 2 candidates
    float4 rec = top4[(size_t)row * 64 + lane];
    float k0 = rec.x; int c0 = __float_as_int(rec.y);
    float k1 = rec.z; int c1 = __float_as_int(rec.w);

    // 4 passes: global lex-min with exclusion of previous winners
    int chosen[4] = { -1, -1, -1, -1 };
    #pragma unroll
    for (int p = 0; p < 4; ++p) {
        bool u0 = (c0 == chosen[0]) | (c0 == chosen[1]) | (c0 == chosen[2]) | (c0 == chosen[3]);
        bool u1 = (c1 == chosen[0]) | (c1 == chosen[1]) | (c1 == chosen[2]) | (c1 == chosen[3]);
        float a = u0 ? FLT_MAX : k0; int ai = u0 ? INT_MAX : c0;
        float b = u1 ? FLT_MAX : k1; int bi = u1 ? INT_MAX : c1;
        if (lexlt(b, bi, a, ai)) { a = b; ai = bi; }
        #pragma unroll
        for (int off = 32; off; off >>= 1) {
            float ob = __shfl_xor(a, off); int oi = __shfl_xor(ai, off);
            if (lexlt(ob, oi, a, ai)) { a = ob; ai = oi; }
        }
        chosen[p] = ai;    // all lanes agree
    }

    // exact fp32 rescore of the 4 survivors (round-1-validated formula)
    float4 xv = *(const float4*)(x + (size_t)row * E + lane * 4);
    float d[4];
    #pragma unroll
    for (int j = 0; j < 4; ++j) {
        float4 wv = *(const float4*)(w + (size_t)chosen[j] * E + lane * 4);
        d[j] = xv.x * wv.x + xv.y * wv.y + xv.z * wv.z + xv.w * wv.w;
    }
    #pragma unroll
    for (int off = 32; off; off >>= 1) {
        #pragma unroll
        for (int j = 0; j < 4; ++j) d[j] += __shfl_xor(d[j], off);
    }

    float X2 = x2[row];
    float bs = FLT_MAX; int win = INT_MAX;
    #pragma unroll
    for (int j = 0; j < 4; ++j) {
        float s = (X2 - 2.0f * d[j]) + w2[chosen[j]];
        if (lexlt(s, chosen[j], bs, win)) { bs = s; win = chosen[j]; }
    }

    if (lane == 0) qidx[row] = (float)win;
    *(float4*)(qdata + (size_t)row * E + lane * 4) =
        *(const float4*)(w + (size_t)win * E + lane * 4);
}

// ---------------------------------------------------------------------------
// Round-1 fp32 fallback (only if ws_size too small). Passed absmax 0.
// ---------------------------------------------------------------------------
constexpr int FBM = 64, FBN = 128, FBK = 64, FPAD = 4, FTH = 256;

__global__ __launch_bounds__(64) void row_sumsq_kernel(const float* __restrict__ src,
                                                       float* __restrict__ dst) {
    int row = blockIdx.x, lane = threadIdx.x;
    float4 v = ((const float4*)(src + (size_t)row * E))[lane];
    float s = v.x * v.x + v.y * v.y + v.z * v.z + v.w * v.w;
    #pragma unroll
    for (int off = 32; off > 0; off >>= 1) s += __shfl_down(s, off);
    if (lane == 0) dst[row] = s;
}

__global__ __launch_bounds__(FTH) void vq_fallback_kernel(
    const float* __restrict__ x, const float* __restrict__ w,
    const float* __restrict__ x2, const float* __restrict__ w2,
    float* __restrict__ qdata, float* __restrict__ qidx)
{
    __shared__ float xs[FBM][FBK + FPAD];
    __shared__ float ws[FBN][FBK + FPAD];
    __shared__ float redS[FBM][16];
    __shared__ int   redC[FBM][16];
    __shared__ int   bestC[FBM];

    const int tid = threadIdx.x, tr = tid >> 4, tc = tid & 15;
    const int r0 = blockIdx.x * FBM;
    float best[4]; int bidx[4];
    #pragma unroll
    for (int i = 0; i < 4; ++i) { best[i] = FLT_MAX; bidx[i] = 0x7FFFFFFF; }
    float x2r[4];
    #pragma unroll
    for (int i = 0; i < 4; ++i) x2r[i] = x2[r0 + tr + 16 * i];

    for (int qt = 0; qt < Qn / FBN; ++qt) {
        const int c0 = qt * FBN;
        float acc[4][8];
        #pragma unroll
        for (int i = 0; i < 4; ++i)
            #pragma unroll
            for (int j = 0; j < 8; ++j) acc[i][j] = 0.f;
        for (int kt = 0; kt < E / FBK; ++kt) {
            __syncthreads();
            const int kk = (tid & 15) * 4, rr = tid >> 4;
            #pragma unroll
            for (int m = 0; m < 4; ++m)
                *(float4*)&xs[m * 16 + rr][kk] =
                    *(const float4*)(x + (size_t)(r0 + m * 16 + rr) * E + kt * FBK + kk);
            #pragma unroll
            for (int m = 0; m < 8; ++m)
                *(float4*)&ws[m * 16 + rr][kk] =
                    *(const float4*)(w + (size_t)(c0 + m * 16 + rr) * E + kt * FBK + kk);
            __syncthreads();
            #pragma unroll
            for (int k4 = 0; k4 < FBK / 4; ++k4) {
                float4 a[4], bb[8];
                #pragma unroll
                for (int i = 0; i < 4; ++i) a[i] = *(const float4*)&xs[tr + 16 * i][k4 * 4];
                #pragma unroll
                for (int j = 0; j < 8; ++j) bb[j] = *(const float4*)&ws[tc + 16 * j][k4 * 4];
                #pragma unroll
                for (int i = 0; i < 4; ++i)
                    #pragma unroll
                    for (int j = 0; j < 8; ++j) {
                        acc[i][j] += a[i].x * bb[j].x; acc[i][j] += a[i].y * bb[j].y;
                        acc[i][j] += a[i].z * bb[j].z; acc[i][j] += a[i].w * bb[j].w;
                    }
            }
        }
        #pragma unroll
        for (int i = 0; i < 4; ++i)
            #pragma unroll
            for (int j = 0; j < 8; ++j) {
                int c = c0 + tc + 16 * j;
                float s = (x2r[i] - 2.0f * acc[i][j]) + w2[c];
                if (s < best[i]) { best[i] = s; bidx[i] = c; }
            }
    }
    #pragma unroll
    for (int i = 0; i < 4; ++i) { redS[tr + 16 * i][tc] = best[i]; redC[tr + 16 * i][tc] = bidx[i]; }
    __syncthreads();
    if (tid < FBM) {
        float bs = FLT_MAX; int bc = 0x7FFFFFFF;
        #pragma unroll
        for (int t = 0; t < 16; ++t) {
            float s = redS[tid][t]; int c = redC[tid][t];
            if (s < bs || (s == bs && c < bc)) { bs = s; bc = c; }
        }
        qidx[r0 + tid] = (float)bc; bestC[tid] = bc;
    }
    __syncthreads();
    for (int it = 0; it < FBM / 4; ++it) {
        int row = it * 4 + (tid >> 6), c = bestC[row], kk = (tid & 63) * 4;
        *(float4*)(qdata + (size_t)(r0 + row) * E + kk) = *(const float4*)(w + (size_t)c * E + kk);
    }
}

// ---------------------------------------------------------------------------
extern "C" void kernel_launch(void* const* d_in, const int* in_sizes, int n_in,
                              void* d_out, int out_size, void* d_ws, size_t ws_size,
                              hipStream_t stream) {
    const float* x = (const float*)d_in[0];
    const float* w = (const float*)d_in[1];
    const int N = in_sizes[0] / E;                      // 32768

    float* qdata = (float*)d_out;
    float* qidx  = (float*)d_out + (size_t)N * E;

    size_t off = 0;
    auto carve = [&](size_t bytes) { size_t p = off; off += (bytes + 255) & ~(size_t)255; return p; };
    size_t oA16 = carve((size_t)N  * 256 * sizeof(_Float16));     // 16.8 MB
    size_t oB16 = carve((size_t)Qn * 256 * sizeof(_Float16));     //  2.1 MB
    size_t ox2  = carve((size_t)N * sizeof(float));
    size_t ow2  = carve((size_t)Qn * sizeof(float));
    size_t oT   = carve((size_t)N * 64 * sizeof(float4));         // 33.6 MB

    if (ws_size >= off && (N % 128) == 0) {
        char* ws = (char*)d_ws;
        _Float16* A16 = (_Float16*)(ws + oA16);
        _Float16* B16 = (_Float16*)(ws + oB16);
        float* x2    = (float*)(ws + ox2);
        float* w2    = (float*)(ws + ow2);
        float4* top4 = (float4*)(ws + oT);

        prep_kernel<<<N / 4 + Qn / 4, 256, 0, stream>>>(x, w, A16, B16, x2, w2, N / 4);
        vq_mfma_kernel<<<dim3(N / 128, Qn / 128), 256, 0, stream>>>(A16, B16, w2, top4);
        finalize_kernel<<<N / 4, 256, 0, stream>>>(top4, x, w, x2, w2, qdata, qidx);
    } else {
        float* x2 = (float*)d_ws;
        float* w2 = x2 + N;
        row_sumsq_kernel<<<N, 64, 0, stream>>>(x, x2);
        row_sumsq_kernel<<<Qn, 64, 0, stream>>>(w, w2);
        vq_fallback_kernel<<<N / FBM, FTH, 0, stream>>>(x, w, x2, w2, qdata, qidx);
    }
}

// Round 8
// 211.407 us; speedup vs baseline: 2.9814x; 1.0523x over previous
//
#include <hip/hip_runtime.h>
#include <cfloat>
#include <climits>

// Problem constants: x (16,2048,256) fp32 -> N=32768 rows; weight (4096,256) fp32.
constexpr int E  = 256;    // quantizing_dim
constexpr int Qn = 4096;   // num_quantizing
constexpr float WSCALE = 4096.0f;   // 2^12 exact pow2 (keeps f16 products well-scaled)

// Round 8: rank by dot only (w2 dropped from approx key; its spread ~2.3e-4 is
// absorbed by the rescue window), keys packed (acc_bits&~0xFFF)|q -> branch-free
// top-2 via med3/max (4 VALU/key, no LDS). Rescue: per-cg top-4 -> global top-8
// -> exact fp32 rescore (reference formula + lex tie-break, validated r1-r7).

typedef _Float16 half8  __attribute__((ext_vector_type(8)));
typedef _Float16 half4v __attribute__((ext_vector_type(4)));
typedef float    f32x16 __attribute__((ext_vector_type(16)));

#define GAS __attribute__((address_space(1)))
#define LAS __attribute__((address_space(3)))

#define NEG_INF __int_as_float(0xFF800000)

__device__ inline bool lexlt(float a, int ai, float b, int bi) {
    return a < b || (a == b && ai < bi);
}

// ---------------------------------------------------------------------------
// Prep: one 64-lane wave per row (x and w). Emits f16 operand + sumsq.
// ---------------------------------------------------------------------------
__global__ __launch_bounds__(256) void prep_kernel(
    const float* __restrict__ x, const float* __restrict__ w,
    _Float16* __restrict__ A16, _Float16* __restrict__ B16,
    float* __restrict__ x2, float* __restrict__ w2, int nxblocks)
{
    int blk  = blockIdx.x;
    int sub  = threadIdx.x >> 6;
    int lane = threadIdx.x & 63;
    bool isX = blk < nxblocks;
    int row  = (isX ? blk : blk - nxblocks) * 4 + sub;

    const float* src = isX ? x : w;
    float4 v = *(const float4*)(src + (size_t)row * E + lane * 4);

    float s = v.x * v.x + v.y * v.y + v.z * v.z + v.w * v.w;   // UNSCALED sumsq
    #pragma unroll
    for (int off = 32; off; off >>= 1) s += __shfl_xor(s, off);
    if (lane == 0) (isX ? x2 : w2)[row] = s;

    float sc = isX ? 1.0f : WSCALE;                            // exact pow2
    half4v h = { (_Float16)(v.x * sc), (_Float16)(v.y * sc),
                 (_Float16)(v.z * sc), (_Float16)(v.w * sc) };
    _Float16* dst16 = (isX ? A16 : B16) + (size_t)row * 256;
    *(half4v*)(dst16 + lane * 4) = h;
}

// ---------------------------------------------------------------------------
// Main MFMA kernel: block = 128 x-rows x 128 codewords, grid (N/128, Qn/128).
// K=256 f16 GEMM; epilogue keeps per-lane packed top-2 (maximize dot), merged
// to per-(row,cg) top-4 packed floats (one float4).
// ---------------------------------------------------------------------------
__device__ inline void ins4max(float K[4], float k) {
    #pragma unroll
    for (int t = 0; t < 4; ++t) {            // keep K descending
        float mx = fmaxf(K[t], k);
        k = fminf(K[t], k);
        K[t] = mx;
    }
}

union SmemU {
    struct { _Float16 W[128 * 64]; _Float16 X[128 * 64]; } st;  // 32 KB staging
    float2 mergeS[128 * 4];                                      // 4 KB (post-loop)
};

__global__ __launch_bounds__(256, 4) void vq_mfma_kernel(
    const _Float16* __restrict__ A16,      // (N, 256)  xh
    const _Float16* __restrict__ B16,      // (Qn, 256) wh_s
    float4* __restrict__ top4)             // (N, 32) packed {k0,k1,k2,k3} desc
{
    __shared__ SmemU sm;

    const int tid  = threadIdx.x;
    const int w    = tid >> 6;
    const int lane = tid & 63;
    const int l31  = lane & 31;
    const int lh   = lane >> 5;          // k-half select
    const int rb   = blockIdx.x;         // row band (128 x-rows)
    const int cg   = blockIdx.y;         // col group (128 codewords)

    const int wr = (w & 1) * 64;         // wave's x-row quadrant base
    const int wc = (w >> 1) * 64;        // wave's codeword quadrant base

    f32x16 acc[2][2];
    #pragma unroll
    for (int f = 0; f < 2; ++f)
        #pragma unroll
        for (int g = 0; g < 2; ++g)
            #pragma unroll
            for (int r = 0; r < 16; ++r) acc[f][g][r] = 0.0f;

    const _Float16* Ab16 = A16 + (size_t)rb * 128 * 256;
    const _Float16* Bb16 = B16 + (size_t)cg * 128 * 256;

    const int srow = lane >> 3;   // staging: row-in-8 group
    const int schk = lane & 7;    // staging: dest 16B chunk

    for (int kt = 0; kt < 4; ++kt) {
        __syncthreads();
        #pragma unroll
        for (int inst = 0; inst < 4; ++inst) {
            int drow = w * 32 + inst * 8 + srow;          // 0..127
            int gchk = schk ^ (drow & 7);                 // source chunk swizzle
            const _Float16* gW = Bb16 + (size_t)drow * 256 + kt * 64 + gchk * 8;
            const _Float16* gX = Ab16 + (size_t)drow * 256 + kt * 64 + gchk * 8;
            __builtin_amdgcn_global_load_lds((const GAS void*)gW,
                (LAS void*)(sm.st.W + w * 2048 + inst * 512), 16, 0, 0);
            __builtin_amdgcn_global_load_lds((const GAS void*)gX,
                (LAS void*)(sm.st.X + w * 2048 + inst * 512), 16, 0, 0);
        }
        __syncthreads();

        #pragma unroll
        for (int s = 0; s < 4; ++s) {
            const int kc = 2 * s + lh;
            half8 wf[2], xf[2];
            #pragma unroll
            for (int f = 0; f < 2; ++f) {
                int fr = wc + 32 * f + l31;
                wf[f] = *(const half8*)(sm.st.W + fr * 64 + ((kc ^ (fr & 7)) << 3));
                int xr = wr + 32 * f + l31;
                xf[f] = *(const half8*)(sm.st.X + xr * 64 + ((kc ^ (xr & 7)) << 3));
            }
            #pragma unroll
            for (int f = 0; f < 2; ++f)
                #pragma unroll
                for (int g = 0; g < 2; ++g)
                    acc[f][g] = __builtin_amdgcn_mfma_f32_32x32x16_f16(
                        wf[f], xf[g], acc[f][g], 0, 0, 0);
        }
    }

    // ---- epilogue: packed key = (bits(acc) & ~0xFFF) | qg; maximize ----
    float t1[2] = { NEG_INF, NEG_INF }, t2[2] = { NEG_INF, NEG_INF };

    #pragma unroll
    for (int f = 0; f < 2; ++f)
        #pragma unroll
        for (int r = 0; r < 16; ++r) {
            int m  = (r & 3) + 8 * (r >> 2) + 4 * lh;     // C-row mapping (32x32)
            int qg = cg * 128 + wc + 32 * f + m;          // global codeword id
            #pragma unroll
            for (int g = 0; g < 2; ++g) {
                float pk = __int_as_float(
                    (__float_as_int(acc[f][g][r]) & 0xFFFFF000) | qg);
                t2[g] = __builtin_amdgcn_fmed3f(t1[g], t2[g], pk);
                t1[g] = fmaxf(t1[g], pk);
            }
        }

    __syncthreads();   // staging reads done -> overlay mergeS

    #pragma unroll
    for (int g = 0; g < 2; ++g) {
        int rrow = wr + 32 * g + l31;
        sm.mergeS[rrow * 4 + ((w >> 1) * 2 + lh)] = make_float2(t1[g], t2[g]);
    }
    __syncthreads();

    if (tid < 128) {
        float K[4] = { NEG_INF, NEG_INF, NEG_INF, NEG_INF };
        #pragma unroll
        for (int sl = 0; sl < 4; ++sl) {
            float2 a = sm.mergeS[tid * 4 + sl];
            ins4max(K, a.x);
            ins4max(K, a.y);
        }
        top4[(size_t)(rb * 128 + tid) * 32 + cg] =
            make_float4(K[0], K[1], K[2], K[3]);
    }
}

// ---------------------------------------------------------------------------
// Finalize: per row, 32 cg x top-4 packed candidates -> global top-8 by packed
// key (wave-max passes w/ bitwise invalidation) -> exact fp32 rescore
// (reference formula + first-index tie-break), write outputs. 1 wave per row.
// ---------------------------------------------------------------------------
__global__ __launch_bounds__(256) void finalize_kernel(
    const float4* __restrict__ top4, const float* __restrict__ x,
    const float* __restrict__ w, const float* __restrict__ x2,
    const float* __restrict__ w2, float* __restrict__ qdata,
    float* __restrict__ qidx)
{
    int row  = blockIdx.x * 4 + (threadIdx.x >> 6);
    int lane = threadIdx.x & 63;

    float cand[4];
    if (lane < 32) {
        float4 c4 = top4[(size_t)row * 32 + lane];
        cand[0] = c4.x; cand[1] = c4.y; cand[2] = c4.z; cand[3] = c4.w;
    } else {
        cand[0] = cand[1] = cand[2] = cand[3] = NEG_INF;
    }

    int chosen[8];
    #pragma unroll
    for (int p = 0; p < 8; ++p) {
        float cur = fmaxf(fmaxf(cand[0], cand[1]), fmaxf(cand[2], cand[3]));
        #pragma unroll
        for (int off = 32; off; off >>= 1)
            cur = fmaxf(cur, __shfl_xor(cur, off));
        int curb = __float_as_int(cur);
        chosen[p] = curb & 0xFFF;
        #pragma unroll
        for (int j = 0; j < 4; ++j)
            if (__float_as_int(cand[j]) == curb) cand[j] = NEG_INF;
    }

    // exact fp32 rescore of the 8 survivors (round-1-validated formula)
    float4 xv = *(const float4*)(x + (size_t)row * E + lane * 4);
    float d[8];
    #pragma unroll
    for (int j = 0; j < 8; ++j) {
        float4 wv = *(const float4*)(w + (size_t)chosen[j] * E + lane * 4);
        d[j] = xv.x * wv.x + xv.y * wv.y + xv.z * wv.z + xv.w * wv.w;
    }
    #pragma unroll
    for (int off = 32; off; off >>= 1) {
        #pragma unroll
        for (int j = 0; j < 8; ++j) d[j] += __shfl_xor(d[j], off);
    }

    float X2 = x2[row];
    float bs = FLT_MAX; int win = INT_MAX;
    #pragma unroll
    for (int j = 0; j < 8; ++j) {
        float s = (X2 - 2.0f * d[j]) + w2[chosen[j]];
        if (lexlt(s, chosen[j], bs, win)) { bs = s; win = chosen[j]; }
    }

    if (lane == 0) qidx[row] = (float)win;
    *(float4*)(qdata + (size_t)row * E + lane * 4) =
        *(const float4*)(w + (size_t)win * E + lane * 4);
}

// ---------------------------------------------------------------------------
// Round-1 fp32 fallback (only if ws_size too small). Passed absmax 0.
// ---------------------------------------------------------------------------
constexpr int FBM = 64, FBN = 128, FBK = 64, FPAD = 4, FTH = 256;

__global__ __launch_bounds__(64) void row_sumsq_kernel(const float* __restrict__ src,
                                                       float* __restrict__ dst) {
    int row = blockIdx.x, lane = threadIdx.x;
    float4 v = ((const float4*)(src + (size_t)row * E))[lane];
    float s = v.x * v.x + v.y * v.y + v.z * v.z + v.w * v.w;
    #pragma unroll
    for (int off = 32; off > 0; off >>= 1) s += __shfl_down(s, off);
    if (lane == 0) dst[row] = s;
}

__global__ __launch_bounds__(FTH) void vq_fallback_kernel(
    const float* __restrict__ x, const float* __restrict__ w,
    const float* __restrict__ x2, const float* __restrict__ w2,
    float* __restrict__ qdata, float* __restrict__ qidx)
{
    __shared__ float xs[FBM][FBK + FPAD];
    __shared__ float ws[FBN][FBK + FPAD];
    __shared__ float redS[FBM][16];
    __shared__ int   redC[FBM][16];
    __shared__ int   bestC[FBM];

    const int tid = threadIdx.x, tr = tid >> 4, tc = tid & 15;
    const int r0 = blockIdx.x * FBM;
    float best[4]; int bidx[4];
    #pragma unroll
    for (int i = 0; i < 4; ++i) { best[i] = FLT_MAX; bidx[i] = 0x7FFFFFFF; }
    float x2r[4];
    #pragma unroll
    for (int i = 0; i < 4; ++i) x2r[i] = x2[r0 + tr + 16 * i];

    for (int qt = 0; qt < Qn / FBN; ++qt) {
        const int c0 = qt * FBN;
        float acc[4][8];
        #pragma unroll
        for (int i = 0; i < 4; ++i)
            #pragma unroll
            for (int j = 0; j < 8; ++j) acc[i][j] = 0.f;
        for (int kt = 0; kt < E / FBK; ++kt) {
            __syncthreads();
            const int kk = (tid & 15) * 4, rr = tid >> 4;
            #pragma unroll
            for (int m = 0; m < 4; ++m)
                *(float4*)&xs[m * 16 + rr][kk] =
                    *(const float4*)(x + (size_t)(r0 + m * 16 + rr) * E + kt * FBK + kk);
            #pragma unroll
            for (int m = 0; m < 8; ++m)
                *(float4*)&ws[m * 16 + rr][kk] =
                    *(const float4*)(w + (size_t)(c0 + m * 16 + rr) * E + kt * FBK + kk);
            __syncthreads();
            #pragma unroll
            for (int k4 = 0; k4 < FBK / 4; ++k4) {
                float4 a[4], bb[8];
                #pragma unroll
                for (int i = 0; i < 4; ++i) a[i] = *(const float4*)&xs[tr + 16 * i][k4 * 4];
                #pragma unroll
                for (int j = 0; j < 8; ++j) bb[j] = *(const float4*)&ws[tc + 16 * j][k4 * 4];
                #pragma unroll
                for (int i = 0; i < 4; ++i)
                    #pragma unroll
                    for (int j = 0; j < 8; ++j) {
                        acc[i][j] += a[i].x * bb[j].x; acc[i][j] += a[i].y * bb[j].y;
                        acc[i][j] += a[i].z * bb[j].z; acc[i][j] += a[i].w * bb[j].w;
                    }
            }
        }
        #pragma unroll
        for (int i = 0; i < 4; ++i)
            #pragma unroll
            for (int j = 0; j < 8; ++j) {
                int c = c0 + tc + 16 * j;
                float s = (x2r[i] - 2.0f * acc[i][j]) + w2[c];
                if (s < best[i]) { best[i] = s; bidx[i] = c; }
            }
    }
    #pragma unroll
    for (int i = 0; i < 4; ++i) { redS[tr + 16 * i][tc] = best[i]; redC[tr + 16 * i][tc] = bidx[i]; }
    __syncthreads();
    if (tid < FBM) {
        float bs = FLT_MAX; int bc = 0x7FFFFFFF;
        #pragma unroll
        for (int t = 0; t < 16; ++t) {
            float s = redS[tid][t]; int c = redC[tid][t];
            if (s < bs || (s == bs && c < bc)) { bs = s; bc = c; }
        }
        qidx[r0 + tid] = (float)bc; bestC[tid] = bc;
    }
    __syncthreads();
    for (int it = 0; it < FBM / 4; ++it) {
        int row = it * 4 + (tid >> 6), c = bestC[row], kk = (tid & 63) * 4;
        *(float4*)(qdata + (size_t)(r0 + row) * E + kk) = *(const float4*)(w + (size_t)c * E + kk);
    }
}

// ---------------------------------------------------------------------------
extern "C" void kernel_launch(void* const* d_in, const int* in_sizes, int n_in,
                              void* d_out, int out_size, void* d_ws, size_t ws_size,
                              hipStream_t stream) {
    const float* x = (const float*)d_in[0];
    const float* w = (const float*)d_in[1];
    const int N = in_sizes[0] / E;                      // 32768

    float* qdata = (float*)d_out;
    float* qidx  = (float*)d_out + (size_t)N * E;

    size_t off = 0;
    auto carve = [&](size_t bytes) { size_t p = off; off += (bytes + 255) & ~(size_t)255; return p; };
    size_t oA16 = carve((size_t)N  * 256 * sizeof(_Float16));     // 16.8 MB
    size_t oB16 = carve((size_t)Qn * 256 * sizeof(_Float16));     //  2.1 MB
    size_t ox2  = carve((size_t)N * sizeof(float));
    size_t ow2  = carve((size_t)Qn * sizeof(float));
    size_t oT   = carve((size_t)N * 32 * sizeof(float4));         // 16.8 MB

    if (ws_size >= off && (N % 128) == 0) {
        char* ws = (char*)d_ws;
        _Float16* A16 = (_Float16*)(ws + oA16);
        _Float16* B16 = (_Float16*)(ws + oB16);
        float* x2    = (float*)(ws + ox2);
        float* w2    = (float*)(ws + ow2);
        float4* top4 = (float4*)(ws + oT);

        prep_kernel<<<N / 4 + Qn / 4, 256, 0, stream>>>(x, w, A16, B16, x2, w2, N / 4);
        vq_mfma_kernel<<<dim3(N / 128, Qn / 128), 256, 0, stream>>>(A16, B16, top4);
        finalize_kernel<<<N / 4, 256, 0, stream>>>(top4, x, w, x2, w2, qdata, qidx);
    } else {
        float* x2 = (float*)d_ws;
        float* w2 = x2 + N;
        row_sumsq_kernel<<<N, 64, 0, stream>>>(x, x2);
        row_sumsq_kernel<<<Qn, 64, 0, stream>>>(w, w2);
        vq_fallback_kernel<<<N / FBM, FTH, 0, stream>>>(x, w, x2, w2, qdata, qidx);
    }
}

// Round 9
// 201.553 us; speedup vs baseline: 3.1272x; 1.0489x over previous
//
#include <hip/hip_runtime.h>
#include <cfloat>
#include <climits>

// Problem constants: x (16,2048,256) fp32 -> N=32768 rows; weight (4096,256) fp32.
constexpr int E  = 256;    // quantizing_dim
constexpr int Qn = 4096;   // num_quantizing
constexpr float WSCALE = 4096.0f;   // 2^12 exact pow2 (keeps f16 products well-scaled)

// Round 9 = round 8 with finalize rescoring top-4 (was top-8): per-candidate
// approx-key error ~5e-5 vs order-stat spacing ~9e-3 -> lambda~0.007 rivals in
// window; P(ref argmin outside top-4) ~ 1e-10/row. Halves the dominant
// codeword-gather traffic in finalize (268 -> 134 MB).

typedef _Float16 half8  __attribute__((ext_vector_type(8)));
typedef _Float16 half4v __attribute__((ext_vector_type(4)));
typedef float    f32x16 __attribute__((ext_vector_type(16)));

#define GAS __attribute__((address_space(1)))
#define LAS __attribute__((address_space(3)))

#define NEG_INF __int_as_float(0xFF800000)

__device__ inline bool lexlt(float a, int ai, float b, int bi) {
    return a < b || (a == b && ai < bi);
}

// ---------------------------------------------------------------------------
// Prep: one 64-lane wave per row (x and w). Emits f16 operand + sumsq.
// ---------------------------------------------------------------------------
__global__ __launch_bounds__(256) void prep_kernel(
    const float* __restrict__ x, const float* __restrict__ w,
    _Float16* __restrict__ A16, _Float16* __restrict__ B16,
    float* __restrict__ x2, float* __restrict__ w2, int nxblocks)
{
    int blk  = blockIdx.x;
    int sub  = threadIdx.x >> 6;
    int lane = threadIdx.x & 63;
    bool isX = blk < nxblocks;
    int row  = (isX ? blk : blk - nxblocks) * 4 + sub;

    const float* src = isX ? x : w;
    float4 v = *(const float4*)(src + (size_t)row * E + lane * 4);

    float s = v.x * v.x + v.y * v.y + v.z * v.z + v.w * v.w;   // UNSCALED sumsq
    #pragma unroll
    for (int off = 32; off; off >>= 1) s += __shfl_xor(s, off);
    if (lane == 0) (isX ? x2 : w2)[row] = s;

    float sc = isX ? 1.0f : WSCALE;                            // exact pow2
    half4v h = { (_Float16)(v.x * sc), (_Float16)(v.y * sc),
                 (_Float16)(v.z * sc), (_Float16)(v.w * sc) };
    _Float16* dst16 = (isX ? A16 : B16) + (size_t)row * 256;
    *(half4v*)(dst16 + lane * 4) = h;
}

// ---------------------------------------------------------------------------
// Main MFMA kernel: block = 128 x-rows x 128 codewords, grid (N/128, Qn/128).
// K=256 f16 GEMM; epilogue keeps per-lane packed top-2 (maximize dot), merged
// to per-(row,cg) top-4 packed floats (one float4). Identical to round 8.
// ---------------------------------------------------------------------------
__device__ inline void ins4max(float K[4], float k) {
    #pragma unroll
    for (int t = 0; t < 4; ++t) {            // keep K descending
        float mx = fmaxf(K[t], k);
        k = fminf(K[t], k);
        K[t] = mx;
    }
}

union SmemU {
    struct { _Float16 W[128 * 64]; _Float16 X[128 * 64]; } st;  // 32 KB staging
    float2 mergeS[128 * 4];                                      // 4 KB (post-loop)
};

__global__ __launch_bounds__(256, 4) void vq_mfma_kernel(
    const _Float16* __restrict__ A16,      // (N, 256)  xh
    const _Float16* __restrict__ B16,      // (Qn, 256) wh_s
    float4* __restrict__ top4)             // (N, 32) packed {k0,k1,k2,k3} desc
{
    __shared__ SmemU sm;

    const int tid  = threadIdx.x;
    const int w    = tid >> 6;
    const int lane = tid & 63;
    const int l31  = lane & 31;
    const int lh   = lane >> 5;          // k-half select
    const int rb   = blockIdx.x;         // row band (128 x-rows)
    const int cg   = blockIdx.y;         // col group (128 codewords)

    const int wr = (w & 1) * 64;         // wave's x-row quadrant base
    const int wc = (w >> 1) * 64;        // wave's codeword quadrant base

    f32x16 acc[2][2];
    #pragma unroll
    for (int f = 0; f < 2; ++f)
        #pragma unroll
        for (int g = 0; g < 2; ++g)
            #pragma unroll
            for (int r = 0; r < 16; ++r) acc[f][g][r] = 0.0f;

    const _Float16* Ab16 = A16 + (size_t)rb * 128 * 256;
    const _Float16* Bb16 = B16 + (size_t)cg * 128 * 256;

    const int srow = lane >> 3;   // staging: row-in-8 group
    const int schk = lane & 7;    // staging: dest 16B chunk

    for (int kt = 0; kt < 4; ++kt) {
        __syncthreads();
        #pragma unroll
        for (int inst = 0; inst < 4; ++inst) {
            int drow = w * 32 + inst * 8 + srow;          // 0..127
            int gchk = schk ^ (drow & 7);                 // source chunk swizzle
            const _Float16* gW = Bb16 + (size_t)drow * 256 + kt * 64 + gchk * 8;
            const _Float16* gX = Ab16 + (size_t)drow * 256 + kt * 64 + gchk * 8;
            __builtin_amdgcn_global_load_lds((const GAS void*)gW,
                (LAS void*)(sm.st.W + w * 2048 + inst * 512), 16, 0, 0);
            __builtin_amdgcn_global_load_lds((const GAS void*)gX,
                (LAS void*)(sm.st.X + w * 2048 + inst * 512), 16, 0, 0);
        }
        __syncthreads();

        #pragma unroll
        for (int s = 0; s < 4; ++s) {
            const int kc = 2 * s + lh;
            half8 wf[2], xf[2];
            #pragma unroll
            for (int f = 0; f < 2; ++f) {
                int fr = wc + 32 * f + l31;
                wf[f] = *(const half8*)(sm.st.W + fr * 64 + ((kc ^ (fr & 7)) << 3));
                int xr = wr + 32 * f + l31;
                xf[f] = *(const half8*)(sm.st.X + xr * 64 + ((kc ^ (xr & 7)) << 3));
            }
            #pragma unroll
            for (int f = 0; f < 2; ++f)
                #pragma unroll
                for (int g = 0; g < 2; ++g)
                    acc[f][g] = __builtin_amdgcn_mfma_f32_32x32x16_f16(
                        wf[f], xf[g], acc[f][g], 0, 0, 0);
        }
    }

    // ---- epilogue: packed key = (bits(acc) & ~0xFFF) | qg; maximize ----
    float t1[2] = { NEG_INF, NEG_INF }, t2[2] = { NEG_INF, NEG_INF };

    #pragma unroll
    for (int f = 0; f < 2; ++f)
        #pragma unroll
        for (int r = 0; r < 16; ++r) {
            int m  = (r & 3) + 8 * (r >> 2) + 4 * lh;     // C-row mapping (32x32)
            int qg = cg * 128 + wc + 32 * f + m;          // global codeword id
            #pragma unroll
            for (int g = 0; g < 2; ++g) {
                float pk = __int_as_float(
                    (__float_as_int(acc[f][g][r]) & 0xFFFFF000) | qg);
                t2[g] = __builtin_amdgcn_fmed3f(t1[g], t2[g], pk);
                t1[g] = fmaxf(t1[g], pk);
            }
        }

    __syncthreads();   // staging reads done -> overlay mergeS

    #pragma unroll
    for (int g = 0; g < 2; ++g) {
        int rrow = wr + 32 * g + l31;
        sm.mergeS[rrow * 4 + ((w >> 1) * 2 + lh)] = make_float2(t1[g], t2[g]);
    }
    __syncthreads();

    if (tid < 128) {
        float K[4] = { NEG_INF, NEG_INF, NEG_INF, NEG_INF };
        #pragma unroll
        for (int sl = 0; sl < 4; ++sl) {
            float2 a = sm.mergeS[tid * 4 + sl];
            ins4max(K, a.x);
            ins4max(K, a.y);
        }
        top4[(size_t)(rb * 128 + tid) * 32 + cg] =
            make_float4(K[0], K[1], K[2], K[3]);
    }
}

// ---------------------------------------------------------------------------
// Finalize: per row, 32 cg x top-4 packed candidates -> global top-4 by packed
// key (wave-max passes w/ bitwise invalidation) -> exact fp32 rescore
// (reference formula + first-index tie-break), write outputs. 1 wave per row.
// ---------------------------------------------------------------------------
__global__ __launch_bounds__(256) void finalize_kernel(
    const float4* __restrict__ top4, const float* __restrict__ x,
    const float* __restrict__ w, const float* __restrict__ x2,
    const float* __restrict__ w2, float* __restrict__ qdata,
    float* __restrict__ qidx)
{
    int row  = blockIdx.x * 4 + (threadIdx.x >> 6);
    int lane = threadIdx.x & 63;

    float cand[4];
    if (lane < 32) {
        float4 c4 = top4[(size_t)row * 32 + lane];
        cand[0] = c4.x; cand[1] = c4.y; cand[2] = c4.z; cand[3] = c4.w;
    } else {
        cand[0] = cand[1] = cand[2] = cand[3] = NEG_INF;
    }

    int chosen[4];
    #pragma unroll
    for (int p = 0; p < 4; ++p) {
        float cur = fmaxf(fmaxf(cand[0], cand[1]), fmaxf(cand[2], cand[3]));
        #pragma unroll
        for (int off = 32; off; off >>= 1)
            cur = fmaxf(cur, __shfl_xor(cur, off));
        int curb = __float_as_int(cur);
        chosen[p] = curb & 0xFFF;
        #pragma unroll
        for (int j = 0; j < 4; ++j)
            if (__float_as_int(cand[j]) == curb) cand[j] = NEG_INF;
    }

    // exact fp32 rescore of the 4 survivors (round-1-validated formula)
    float4 xv = *(const float4*)(x + (size_t)row * E + lane * 4);
    float d[4];
    #pragma unroll
    for (int j = 0; j < 4; ++j) {
        float4 wv = *(const float4*)(w + (size_t)chosen[j] * E + lane * 4);
        d[j] = xv.x * wv.x + xv.y * wv.y + xv.z * wv.z + xv.w * wv.w;
    }
    #pragma unroll
    for (int off = 32; off; off >>= 1) {
        #pragma unroll
        for (int j = 0; j < 4; ++j) d[j] += __shfl_xor(d[j], off);
    }

    float X2 = x2[row];
    float bs = FLT_MAX; int win = INT_MAX;
    #pragma unroll
    for (int j = 0; j < 4; ++j) {
        float s = (X2 - 2.0f * d[j]) + w2[chosen[j]];
        if (lexlt(s, chosen[j], bs, win)) { bs = s; win = chosen[j]; }
    }

    if (lane == 0) qidx[row] = (float)win;
    *(float4*)(qdata + (size_t)row * E + lane * 4) =
        *(const float4*)(w + (size_t)win * E + lane * 4);
}

// ---------------------------------------------------------------------------
// Round-1 fp32 fallback (only if ws_size too small). Passed absmax 0.
// ---------------------------------------------------------------------------
constexpr int FBM = 64, FBN = 128, FBK = 64, FPAD = 4, FTH = 256;

__global__ __launch_bounds__(64) void row_sumsq_kernel(const float* __restrict__ src,
                                                       float* __restrict__ dst) {
    int row = blockIdx.x, lane = threadIdx.x;
    float4 v = ((const float4*)(src + (size_t)row * E))[lane];
    float s = v.x * v.x + v.y * v.y + v.z * v.z + v.w * v.w;
    #pragma unroll
    for (int off = 32; off > 0; off >>= 1) s += __shfl_down(s, off);
    if (lane == 0) dst[row] = s;
}

__global__ __launch_bounds__(FTH) void vq_fallback_kernel(
    const float* __restrict__ x, const float* __restrict__ w,
    const float* __restrict__ x2, const float* __restrict__ w2,
    float* __restrict__ qdata, float* __restrict__ qidx)
{
    __shared__ float xs[FBM][FBK + FPAD];
    __shared__ float ws[FBN][FBK + FPAD];
    __shared__ float redS[FBM][16];
    __shared__ int   redC[FBM][16];
    __shared__ int   bestC[FBM];

    const int tid = threadIdx.x, tr = tid >> 4, tc = tid & 15;
    const int r0 = blockIdx.x * FBM;
    float best[4]; int bidx[4];
    #pragma unroll
    for (int i = 0; i < 4; ++i) { best[i] = FLT_MAX; bidx[i] = 0x7FFFFFFF; }
    float x2r[4];
    #pragma unroll
    for (int i = 0; i < 4; ++i) x2r[i] = x2[r0 + tr + 16 * i];

    for (int qt = 0; qt < Qn / FBN; ++qt) {
        const int c0 = qt * FBN;
        float acc[4][8];
        #pragma unroll
        for (int i = 0; i < 4; ++i)
            #pragma unroll
            for (int j = 0; j < 8; ++j) acc[i][j] = 0.f;
        for (int kt = 0; kt < E / FBK; ++kt) {
            __syncthreads();
            const int kk = (tid & 15) * 4, rr = tid >> 4;
            #pragma unroll
            for (int m = 0; m < 4; ++m)
                *(float4*)&xs[m * 16 + rr][kk] =
                    *(const float4*)(x + (size_t)(r0 + m * 16 + rr) * E + kt * FBK + kk);
            #pragma unroll
            for (int m = 0; m < 8; ++m)
                *(float4*)&ws[m * 16 + rr][kk] =
                    *(const float4*)(w + (size_t)(c0 + m * 16 + rr) * E + kt * FBK + kk);
            __syncthreads();
            #pragma unroll
            for (int k4 = 0; k4 < FBK / 4; ++k4) {
                float4 a[4], bb[8];
                #pragma unroll
                for (int i = 0; i < 4; ++i) a[i] = *(const float4*)&xs[tr + 16 * i][k4 * 4];
                #pragma unroll
                for (int j = 0; j < 8; ++j) bb[j] = *(const float4*)&ws[tc + 16 * j][k4 * 4];
                #pragma unroll
                for (int i = 0; i < 4; ++i)
                    #pragma unroll
                    for (int j = 0; j < 8; ++j) {
                        acc[i][j] += a[i].x * bb[j].x; acc[i][j] += a[i].y * bb[j].y;
                        acc[i][j] += a[i].z * bb[j].z; acc[i][j] += a[i].w * bb[j].w;
                    }
            }
        }
        #pragma unroll
        for (int i = 0; i < 4; ++i)
            #pragma unroll
            for (int j = 0; j < 8; ++j) {
                int c = c0 + tc + 16 * j;
                float s = (x2r[i] - 2.0f * acc[i][j]) + w2[c];
                if (s < best[i]) { best[i] = s; bidx[i] = c; }
            }
    }
    #pragma unroll
    for (int i = 0; i < 4; ++i) { redS[tr + 16 * i][tc] = best[i]; redC[tr + 16 * i][tc] = bidx[i]; }
    __syncthreads();
    if (tid < FBM) {
        float bs = FLT_MAX; int bc = 0x7FFFFFFF;
        #pragma unroll
        for (int t = 0; t < 16; ++t) {
            float s = redS[tid][t]; int c = redC[tid][t];
            if (s < bs || (s == bs && c < bc)) { bs = s; bc = c; }
        }
        qidx[r0 + tid] = (float)bc; bestC[tid] = bc;
    }
    __syncthreads();
    for (int it = 0; it < FBM / 4; ++it) {
        int row = it * 4 + (tid >> 6), c = bestC[row], kk = (tid & 63) * 4;
        *(float4*)(qdata + (size_t)(r0 + row) * E + kk) = *(const float4*)(w + (size_t)c * E + kk);
    }
}

// ---------------------------------------------------------------------------
extern "C" void kernel_launch(void* const* d_in, const int* in_sizes, int n_in,
                              void* d_out, int out_size, void* d_ws, size_t ws_size,
                              hipStream_t stream) {
    const float* x = (const float*)d_in[0];
    const float* w = (const float*)d_in[1];
    const int N = in_sizes[0] / E;                      // 32768

    float* qdata = (float*)d_out;
    float* qidx  = (float*)d_out + (size_t)N * E;

    size_t off = 0;
    auto carve = [&](size_t bytes) { size_t p = off; off += (bytes + 255) & ~(size_t)255; return p; };
    size_t oA16 = carve((size_t)N  * 256 * sizeof(_Float16));     // 16.8 MB
    size_t oB16 = carve((size_t)Qn * 256 * sizeof(_Float16));     //  2.1 MB
    size_t ox2  = carve((size_t)N * sizeof(float));
    size_t ow2  = carve((size_t)Qn * sizeof(float));
    size_t oT   = carve((size_t)N * 32 * sizeof(float4));         // 16.8 MB

    if (ws_size >= off && (N % 128) == 0) {
        char* ws = (char*)d_ws;
        _Float16* A16 = (_Float16*)(ws + oA16);
        _Float16* B16 = (_Float16*)(ws + oB16);
        float* x2    = (float*)(ws + ox2);
        float* w2    = (float*)(ws + ow2);
        float4* top4 = (float4*)(ws + oT);

        prep_kernel<<<N / 4 + Qn / 4, 256, 0, stream>>>(x, w, A16, B16, x2, w2, N / 4);
        vq_mfma_kernel<<<dim3(N / 128, Qn / 128), 256, 0, stream>>>(A16, B16, top4);
        finalize_kernel<<<N / 4, 256, 0, stream>>>(top4, x, w, x2, w2, qdata, qidx);
    } else {
        float* x2 = (float*)d_ws;
        float* w2 = x2 + N;
        row_sumsq_kernel<<<N, 64, 0, stream>>>(x, x2);
        row_sumsq_kernel<<<Qn, 64, 0, stream>>>(w, w2);
        vq_fallback_kernel<<<N / FBM, FTH, 0, stream>>>(x, w, x2, w2, qdata, qidx);
    }
}